// Round 1
// baseline (315.063 us; speedup 1.0000x reference)
//
#include <hip/hip_runtime.h>
#include <math.h>

#define HW_N   3136
#define W_DIM  56
#define C_IN   256
#define C_R    32
#define C_OUT  256
#define C_ALL  320
#define K2D    49
#define BN_EPS 1e-5f

__device__ __forceinline__ int refl(int v) {
    v = (v < 0) ? -v : v;
    return (v > 55) ? (110 - v) : v;
}

// ---------------------------------------------------------------------------
// Kernel 1: fused conv1x1 for x1|x2|x3 -> xall[b][pos][320]
//   co 0..31 = x1 (w1c,b1c), 32..63 = x2 (w2c,b2c), 64..319 = x3 (w3c,b3c)
// Tile: 64 co x 64 pos per block, 256 threads, reg tile 4x4.
// ---------------------------------------------------------------------------
__global__ __launch_bounds__(256) void k_conv(
    const float* __restrict__ x,
    const float* __restrict__ w1c, const float* __restrict__ b1c,
    const float* __restrict__ w2c, const float* __restrict__ b2c,
    const float* __restrict__ w3c, const float* __restrict__ b3c,
    float* __restrict__ xall)
{
    __shared__ __align__(16) float xs[64][68];
    __shared__ __align__(16) float wl[64][68];
    const int tid  = threadIdx.x;
    const int b    = blockIdx.z;
    const int cot  = blockIdx.y;          // 0..4  (co tile of 64)
    const int pos0 = blockIdx.x * 64;     // pos tile

    const int lr  = tid >> 4;             // 0..15
    const int lc4 = (tid & 15) * 4;       // 0..60 step 4
    const int co0 = (tid >> 4) * 4;       // 0..60 step 4
    const int pp0 = (tid & 15) * 4;       // 0..60 step 4

    float acc[4][4];
#pragma unroll
    for (int j = 0; j < 4; ++j)
#pragma unroll
        for (int p = 0; p < 4; ++p) acc[j][p] = 0.f;

    for (int ch = 0; ch < 4; ++ch) {
        const int cib = ch * 64;
#pragma unroll
        for (int r = 0; r < 4; ++r) {
            const int ci = lr + 16 * r;
            *(float4*)&xs[ci][lc4] =
                *(const float4*)(x + ((size_t)b * C_IN + cib + ci) * HW_N + pos0 + lc4);
        }
#pragma unroll
        for (int r = 0; r < 4; ++r) {
            const int col = lr + 16 * r;
            const int cog = cot * 64 + col;
            const float* wp = (cog < 32) ? (w1c + cog * C_IN)
                            : (cog < 64) ? (w2c + (cog - 32) * C_IN)
                                         : (w3c + (cog - 64) * C_IN);
            *(float4*)&wl[col][lc4] = *(const float4*)(wp + cib + lc4);
        }
        __syncthreads();
#pragma unroll
        for (int c4 = 0; c4 < 16; ++c4) {
            const int ci = c4 * 4;
            const float4 a0 = *(const float4*)&wl[co0 + 0][ci];
            const float4 a1 = *(const float4*)&wl[co0 + 1][ci];
            const float4 a2 = *(const float4*)&wl[co0 + 2][ci];
            const float4 a3 = *(const float4*)&wl[co0 + 3][ci];
            const float4 b0 = *(const float4*)&xs[ci + 0][pp0];
            const float4 b1 = *(const float4*)&xs[ci + 1][pp0];
            const float4 b2 = *(const float4*)&xs[ci + 2][pp0];
            const float4 b3 = *(const float4*)&xs[ci + 3][pp0];
#define FMA_ROW(AJ, J)                                                   \
            acc[J][0] += AJ.x*b0.x + AJ.y*b1.x + AJ.z*b2.x + AJ.w*b3.x;  \
            acc[J][1] += AJ.x*b0.y + AJ.y*b1.y + AJ.z*b2.y + AJ.w*b3.y;  \
            acc[J][2] += AJ.x*b0.z + AJ.y*b1.z + AJ.z*b2.z + AJ.w*b3.z;  \
            acc[J][3] += AJ.x*b0.w + AJ.y*b1.w + AJ.z*b2.w + AJ.w*b3.w;
            FMA_ROW(a0, 0) FMA_ROW(a1, 1) FMA_ROW(a2, 2) FMA_ROW(a3, 3)
#undef FMA_ROW
        }
        __syncthreads();
    }

    // bias + transpose through LDS -> coalesced [pos][co] stores
#pragma unroll
    for (int j = 0; j < 4; ++j) {
        const int cog = cot * 64 + co0 + j;
        const float bias = (cog < 32) ? b1c[cog] : (cog < 64) ? b2c[cog - 32] : b3c[cog - 64];
#pragma unroll
        for (int p = 0; p < 4; ++p) xs[pp0 + p][co0 + j] = acc[j][p] + bias;
    }
    __syncthreads();
    const int pl = tid >> 2;
#pragma unroll
    for (int r = 0; r < 4; ++r) {
        const int col = (tid & 3) * 4 + 16 * r;
        *(float4*)(xall + ((size_t)b * HW_N + pos0 + pl) * C_ALL + cot * 64 + col) =
            *(const float4*)&xs[pl][col];
    }
}

// ---------------------------------------------------------------------------
// Kernel 2: fused attention. One wave per pixel, 4 waves per block.
// Writes out_tmp[b][pos][c] (c-contiguous, coalesced); k_transpose fixes layout.
// ---------------------------------------------------------------------------
__global__ __launch_bounds__(256) void k_attn(
    const float* __restrict__ xall,
    const float* __restrict__ bn1_g, const float* __restrict__ bn1_b,
    const float* __restrict__ bn1_m, const float* __restrict__ bn1_v,
    const float* __restrict__ cw1,
    const float* __restrict__ bn2_g, const float* __restrict__ bn2_b,
    const float* __restrict__ bn2_m, const float* __restrict__ bn2_v,
    const float* __restrict__ cw2, const float* __restrict__ cw2_b,
    float* __restrict__ outt)
{
    __shared__ __align__(16) float buf[4][K2D * 36];  // row pad 36: b128-aligned, <=2-way banks
    __shared__ int pk[4][52];
    const int tid = threadIdx.x;
    const int w = tid >> 6, lane = tid & 63;
    const int b = blockIdx.y;
    const int pos = blockIdx.x * 4 + w;
    const int y0 = pos / W_DIM, x0 = pos - y0 * W_DIM;
    const float* __restrict__ base = xall + (size_t)b * HW_N * C_ALL;
    float* bw = buf[w];

    // ---- phase 1: t[k][c] = relu(bn1(x1[c] - x2[pk(k)][c]))
    {
        const int c  = lane & 31;
        const int kh = lane >> 5;
        const float iv = bn1_g[c] * rsqrtf(bn1_v[c] + BN_EPS);
        const float bt = bn1_b[c] - bn1_m[c] * iv;
        const float x1v = base[(size_t)pos * C_ALL + c];
#pragma unroll
        for (int j = 0; j < 25; ++j) {
            const int k = 2 * j + kh;
            if (k < K2D) {
                const int dy = k / 7, dx = k - dy * 7;
                const int rp = refl(y0 + dy - 3) * W_DIM + refl(x0 + dx - 3);
                if (c == 0) pk[w][k] = rp;
                const float x2v = base[(size_t)rp * C_ALL + 32 + c];
                bw[k * 36 + c] = fmaxf((x1v - x2v) * iv + bt, 0.f);
            }
        }
    }
    __syncthreads();

    const int o2 = lane & 15, kq = lane >> 4;   // lane = kq*16 + o2
    float4 rA[8], rB[8];
    float accA[13], accB[13];

    // ---- phase 2: y1[o][k] = sum_c cw1[o][c] * t[k][c]   (o in {o2, o2+16})
#pragma unroll
    for (int q = 0; q < 8; ++q) {
        rA[q] = *(const float4*)(cw1 + o2 * C_R + q * 4);
        rB[q] = *(const float4*)(cw1 + (o2 + 16) * C_R + q * 4);
    }
#pragma unroll
    for (int j = 0; j < 13; ++j) { accA[j] = 0.f; accB[j] = 0.f; }
#pragma unroll
    for (int j = 0; j < 13; ++j) {
        const int k = 4 * j + kq;
        if (k < K2D) {
#pragma unroll
            for (int q = 0; q < 8; ++q) {
                const float4 t = *(const float4*)&bw[k * 36 + q * 4];
                accA[j] += rA[q].x*t.x + rA[q].y*t.y + rA[q].z*t.z + rA[q].w*t.w;
                accB[j] += rB[q].x*t.x + rB[q].y*t.y + rB[q].z*t.z + rB[q].w*t.w;
            }
        }
    }
    __syncthreads();
    // bn2 + relu, write y2[k][o]
    {
        const float ivA = bn2_g[o2] * rsqrtf(bn2_v[o2] + BN_EPS);
        const float btA = bn2_b[o2] - bn2_m[o2] * ivA;
        const float ivB = bn2_g[o2 + 16] * rsqrtf(bn2_v[o2 + 16] + BN_EPS);
        const float btB = bn2_b[o2 + 16] - bn2_m[o2 + 16] * ivB;
#pragma unroll
        for (int j = 0; j < 13; ++j) {
            const int k = 4 * j + kq;
            if (k < K2D) {
                bw[k * 36 + o2]      = fmaxf(accA[j] * ivA + btA, 0.f);
                bw[k * 36 + o2 + 16] = fmaxf(accB[j] * ivB + btB, 0.f);
            }
        }
    }
    __syncthreads();

    // ---- phase 3: logits[h][k] = cw2_b[h] + sum_o cw2[h][o] * y2[k][o]
#pragma unroll
    for (int q = 0; q < 8; ++q) {
        rA[q] = *(const float4*)(cw2 + o2 * C_R + q * 4);
        rB[q] = *(const float4*)(cw2 + (o2 + 16) * C_R + q * 4);
    }
    {
        const float bsA = cw2_b[o2], bsB = cw2_b[o2 + 16];
#pragma unroll
        for (int j = 0; j < 13; ++j) { accA[j] = bsA; accB[j] = bsB; }
    }
#pragma unroll
    for (int j = 0; j < 13; ++j) {
        const int k = 4 * j + kq;
        if (k < K2D) {
#pragma unroll
            for (int q = 0; q < 8; ++q) {
                const float4 t = *(const float4*)&bw[k * 36 + q * 4];
                accA[j] += rA[q].x*t.x + rA[q].y*t.y + rA[q].z*t.z + rA[q].w*t.w;
                accB[j] += rB[q].x*t.x + rB[q].y*t.y + rB[q].z*t.z + rB[q].w*t.w;
            }
        }
    }
    __syncthreads();

    // ---- phase 4: softmax over k per head; k is split across kq lanes + j regs
    {
        float mA = -1e30f, mB = -1e30f;
#pragma unroll
        for (int j = 0; j < 13; ++j) {
            const int k = 4 * j + kq;
            if (k < K2D) { mA = fmaxf(mA, accA[j]); mB = fmaxf(mB, accB[j]); }
        }
        mA = fmaxf(mA, __shfl_xor(mA, 16, 64));
        mA = fmaxf(mA, __shfl_xor(mA, 32, 64));
        mB = fmaxf(mB, __shfl_xor(mB, 16, 64));
        mB = fmaxf(mB, __shfl_xor(mB, 32, 64));
        float sA = 0.f, sB = 0.f;
#pragma unroll
        for (int j = 0; j < 13; ++j) {
            const int k = 4 * j + kq;
            if (k < K2D) {
                accA[j] = __expf(accA[j] - mA); sA += accA[j];
                accB[j] = __expf(accB[j] - mB); sB += accB[j];
            }
        }
        sA += __shfl_xor(sA, 16, 64); sA += __shfl_xor(sA, 32, 64);
        sB += __shfl_xor(sB, 16, 64); sB += __shfl_xor(sB, 32, 64);
        const float rsA = 1.f / sA, rsB = 1.f / sB;
#pragma unroll
        for (int j = 0; j < 13; ++j) {
            const int k = 4 * j + kq;
            if (k < K2D) {
                bw[k * 36 + o2]      = accA[j] * rsA;
                bw[k * 36 + o2 + 16] = accB[j] * rsB;
            }
        }
    }
    __syncthreads();

    // ---- phase 5: out[c] = sum_k x3[pk[k]][c] * wgt[k][c>>3]; c = 4*lane..+3
    {
        const int hn = lane >> 1;     // (4*lane)/8
        float4 a = make_float4(0.f, 0.f, 0.f, 0.f);
        for (int k = 0; k < K2D; ++k) {
            const int rp = pk[w][k];
            const float wv = bw[k * 36 + hn];
            const float4 v = *(const float4*)(base + (size_t)rp * C_ALL + 64 + lane * 4);
            a.x += v.x * wv; a.y += v.y * wv; a.z += v.z * wv; a.w += v.w * wv;
        }
        *(float4*)(outt + ((size_t)b * HW_N + pos) * C_OUT + lane * 4) = a;
    }
}

// ---------------------------------------------------------------------------
// Kernel 3: transpose [b][i][c] -> [b][c][i]
// ---------------------------------------------------------------------------
__global__ __launch_bounds__(256) void k_transpose(
    const float* __restrict__ in, float* __restrict__ out)
{
    __shared__ float ts[32][33];
    const int tid = threadIdx.x;
    const int b  = blockIdx.z;
    const int i0 = blockIdx.x * 32;
    const int c0 = blockIdx.y * 32;
    const int rr = tid >> 5, cc = tid & 31;
#pragma unroll
    for (int r = 0; r < 4; ++r) {
        const int ii = rr * 4 + r;
        ts[ii][cc] = in[((size_t)b * HW_N + i0 + ii) * C_OUT + c0 + cc];
    }
    __syncthreads();
#pragma unroll
    for (int r = 0; r < 4; ++r) {
        const int ccl = rr * 4 + r;
        out[((size_t)b * C_OUT + c0 + ccl) * HW_N + i0 + cc] = ts[cc][ccl];
    }
}

// ---------------------------------------------------------------------------
extern "C" void kernel_launch(void* const* d_in, const int* in_sizes, int n_in,
                              void* d_out, int out_size, void* d_ws, size_t ws_size,
                              hipStream_t stream)
{
    const float* x     = (const float*)d_in[0];
    const float* w1c   = (const float*)d_in[1];
    const float* b1c   = (const float*)d_in[2];
    const float* w2c   = (const float*)d_in[3];
    const float* b2c   = (const float*)d_in[4];
    const float* w3c   = (const float*)d_in[5];
    const float* b3c   = (const float*)d_in[6];
    const float* bn1_g = (const float*)d_in[7];
    const float* bn1_b = (const float*)d_in[8];
    const float* bn1_m = (const float*)d_in[9];
    const float* bn1_v = (const float*)d_in[10];
    const float* cw1   = (const float*)d_in[11];
    const float* bn2_g = (const float*)d_in[12];
    const float* bn2_b = (const float*)d_in[13];
    const float* bn2_m = (const float*)d_in[14];
    const float* bn2_v = (const float*)d_in[15];
    const float* cw2   = (const float*)d_in[16];
    const float* cw2_b = (const float*)d_in[17];

    float* xall = (float*)d_ws;                              // [4][3136][320]
    float* outt = xall + (size_t)4 * HW_N * C_ALL;           // [4][3136][256]

    k_conv<<<dim3(49, 5, 4), 256, 0, stream>>>(x, w1c, b1c, w2c, b2c, w3c, b3c, xall);
    k_attn<<<dim3(784, 4, 1), 256, 0, stream>>>(xall,
        bn1_g, bn1_b, bn1_m, bn1_v, cw1,
        bn2_g, bn2_b, bn2_m, bn2_v, cw2, cw2_b, outt);
    k_transpose<<<dim3(98, 8, 4), 256, 0, stream>>>(outt, (float*)d_out);
}

// Round 2
// 293.669 us; speedup vs baseline: 1.0729x; 1.0729x over previous
//
#include <hip/hip_runtime.h>
#include <math.h>

#define HW_N   3136
#define W_DIM  56
#define C_IN   256
#define C_R    32
#define C_OUT  256
#define C_ALL  320
#define K2D    49
#define BN_EPS 1e-5f

__device__ __forceinline__ int refl(int v) {
    v = (v < 0) ? -v : v;
    return (v > 55) ? (110 - v) : v;
}

// Wave-local "barrier": buf[w]/pk[w] are wave-private, so cross-lane LDS
// exchange within one wave only needs (a) DS pipe drained (lgkmcnt) and
// (b) a compiler reordering fence. No s_barrier -> waves never rendezvous.
__device__ __forceinline__ void wave_fence() {
    asm volatile("s_waitcnt lgkmcnt(0)" ::: "memory");
}

// ---------------------------------------------------------------------------
// Kernel 1: fused conv1x1 for x1|x2|x3 -> xall[b][pos][320]
//   co 0..31 = x1 (w1c,b1c), 32..63 = x2 (w2c,b2c), 64..319 = x3 (w3c,b3c)
// Tile: 64 co x 64 pos per block, 256 threads, reg tile 4x4.
// ---------------------------------------------------------------------------
__global__ __launch_bounds__(256) void k_conv(
    const float* __restrict__ x,
    const float* __restrict__ w1c, const float* __restrict__ b1c,
    const float* __restrict__ w2c, const float* __restrict__ b2c,
    const float* __restrict__ w3c, const float* __restrict__ b3c,
    float* __restrict__ xall)
{
    __shared__ __align__(16) float xs[64][68];
    __shared__ __align__(16) float wl[64][68];
    const int tid  = threadIdx.x;
    const int b    = blockIdx.z;
    const int cot  = blockIdx.y;          // 0..4  (co tile of 64)
    const int pos0 = blockIdx.x * 64;     // pos tile

    const int lr  = tid >> 4;             // 0..15
    const int lc4 = (tid & 15) * 4;       // 0..60 step 4
    const int co0 = (tid >> 4) * 4;       // 0..60 step 4
    const int pp0 = (tid & 15) * 4;       // 0..60 step 4

    float acc[4][4];
#pragma unroll
    for (int j = 0; j < 4; ++j)
#pragma unroll
        for (int p = 0; p < 4; ++p) acc[j][p] = 0.f;

    for (int ch = 0; ch < 4; ++ch) {
        const int cib = ch * 64;
#pragma unroll
        for (int r = 0; r < 4; ++r) {
            const int ci = lr + 16 * r;
            *(float4*)&xs[ci][lc4] =
                *(const float4*)(x + ((size_t)b * C_IN + cib + ci) * HW_N + pos0 + lc4);
        }
#pragma unroll
        for (int r = 0; r < 4; ++r) {
            const int col = lr + 16 * r;
            const int cog = cot * 64 + col;
            const float* wp = (cog < 32) ? (w1c + cog * C_IN)
                            : (cog < 64) ? (w2c + (cog - 32) * C_IN)
                                         : (w3c + (cog - 64) * C_IN);
            *(float4*)&wl[col][lc4] = *(const float4*)(wp + cib + lc4);
        }
        __syncthreads();
#pragma unroll
        for (int c4 = 0; c4 < 16; ++c4) {
            const int ci = c4 * 4;
            const float4 a0 = *(const float4*)&wl[co0 + 0][ci];
            const float4 a1 = *(const float4*)&wl[co0 + 1][ci];
            const float4 a2 = *(const float4*)&wl[co0 + 2][ci];
            const float4 a3 = *(const float4*)&wl[co0 + 3][ci];
            const float4 b0 = *(const float4*)&xs[ci + 0][pp0];
            const float4 b1 = *(const float4*)&xs[ci + 1][pp0];
            const float4 b2 = *(const float4*)&xs[ci + 2][pp0];
            const float4 b3 = *(const float4*)&xs[ci + 3][pp0];
#define FMA_ROW(AJ, J)                                                   \
            acc[J][0] += AJ.x*b0.x + AJ.y*b1.x + AJ.z*b2.x + AJ.w*b3.x;  \
            acc[J][1] += AJ.x*b0.y + AJ.y*b1.y + AJ.z*b2.y + AJ.w*b3.y;  \
            acc[J][2] += AJ.x*b0.z + AJ.y*b1.z + AJ.z*b2.z + AJ.w*b3.z;  \
            acc[J][3] += AJ.x*b0.w + AJ.y*b1.w + AJ.z*b2.w + AJ.w*b3.w;
            FMA_ROW(a0, 0) FMA_ROW(a1, 1) FMA_ROW(a2, 2) FMA_ROW(a3, 3)
#undef FMA_ROW
        }
        __syncthreads();
    }

    // bias + transpose through LDS -> coalesced [pos][co] stores
#pragma unroll
    for (int j = 0; j < 4; ++j) {
        const int cog = cot * 64 + co0 + j;
        const float bias = (cog < 32) ? b1c[cog] : (cog < 64) ? b2c[cog - 32] : b3c[cog - 64];
#pragma unroll
        for (int p = 0; p < 4; ++p) xs[pp0 + p][co0 + j] = acc[j][p] + bias;
    }
    __syncthreads();
    const int pl = tid >> 2;
#pragma unroll
    for (int r = 0; r < 4; ++r) {
        const int col = (tid & 3) * 4 + 16 * r;
        *(float4*)(xall + ((size_t)b * HW_N + pos0 + pl) * C_ALL + cot * 64 + col) =
            *(const float4*)&xs[pl][col];
    }
}

// ---------------------------------------------------------------------------
// Kernel 2: fused attention. One wave per pixel, 4 waves per block.
// NO block barriers: each wave owns buf[w]/pk[w]; wave_fence() orders the
// wave's own LDS traffic. XCD-swizzled block index for L2 halo locality.
// ---------------------------------------------------------------------------
__global__ __launch_bounds__(256) void k_attn(
    const float* __restrict__ xall,
    const float* __restrict__ bn1_g, const float* __restrict__ bn1_b,
    const float* __restrict__ bn1_m, const float* __restrict__ bn1_v,
    const float* __restrict__ cw1,
    const float* __restrict__ bn2_g, const float* __restrict__ bn2_b,
    const float* __restrict__ bn2_m, const float* __restrict__ bn2_v,
    const float* __restrict__ cw2, const float* __restrict__ cw2_b,
    float* __restrict__ outt)
{
    __shared__ __align__(16) float buf[4][K2D * 36];  // row pad 36: b128-aligned, <=2-way banks
    __shared__ int pk[4][52];
    const int tid = threadIdx.x;
    const int w = tid >> 6, lane = tid & 63;
    const int b = blockIdx.y;
    // XCD swizzle: bid%8 selects XCD (dispatch heuristic); give each XCD a
    // contiguous 98-block (392-pixel) span so halo rows stay in its 4MB L2.
    const int bid  = blockIdx.x;                 // 0..783
    const int posb = (bid & 7) * 98 + (bid >> 3);
    const int pos  = posb * 4 + w;
    const int y0 = pos / W_DIM, x0 = pos - y0 * W_DIM;
    const float* __restrict__ base = xall + (size_t)b * HW_N * C_ALL;
    float* bw = buf[w];

    // ---- phase 1: t[k][c] = relu(bn1(x1[c] - x2[pk(k)][c]))
    {
        const int c  = lane & 31;
        const int kh = lane >> 5;
        const float iv = bn1_g[c] * rsqrtf(bn1_v[c] + BN_EPS);
        const float bt = bn1_b[c] - bn1_m[c] * iv;
        const float x1v = base[(size_t)pos * C_ALL + c];
#pragma unroll
        for (int j = 0; j < 25; ++j) {
            const int k = 2 * j + kh;
            if (k < K2D) {
                const int dy = k / 7, dx = k - dy * 7;
                const int rp = refl(y0 + dy - 3) * W_DIM + refl(x0 + dx - 3);
                if (c == 0) pk[w][k] = rp;
                const float x2v = base[(size_t)rp * C_ALL + 32 + c];
                bw[k * 36 + c] = fmaxf((x1v - x2v) * iv + bt, 0.f);
            }
        }
    }
    wave_fence();

    const int o2 = lane & 15, kq = lane >> 4;   // lane = kq*16 + o2
    float4 rA[8], rB[8];
    float accA[13], accB[13];

    // ---- phase 2: y1[o][k] = sum_c cw1[o][c] * t[k][c]   (o in {o2, o2+16})
#pragma unroll
    for (int q = 0; q < 8; ++q) {
        rA[q] = *(const float4*)(cw1 + o2 * C_R + q * 4);
        rB[q] = *(const float4*)(cw1 + (o2 + 16) * C_R + q * 4);
    }
#pragma unroll
    for (int j = 0; j < 13; ++j) { accA[j] = 0.f; accB[j] = 0.f; }
#pragma unroll
    for (int j = 0; j < 13; ++j) {
        const int k = 4 * j + kq;
        if (k < K2D) {
#pragma unroll
            for (int q = 0; q < 8; ++q) {
                const float4 t = *(const float4*)&bw[k * 36 + q * 4];
                accA[j] += rA[q].x*t.x + rA[q].y*t.y + rA[q].z*t.z + rA[q].w*t.w;
                accB[j] += rB[q].x*t.x + rB[q].y*t.y + rB[q].z*t.z + rB[q].w*t.w;
            }
        }
    }
    wave_fence();
    // bn2 + relu, write y2[k][o]
    {
        const float ivA = bn2_g[o2] * rsqrtf(bn2_v[o2] + BN_EPS);
        const float btA = bn2_b[o2] - bn2_m[o2] * ivA;
        const float ivB = bn2_g[o2 + 16] * rsqrtf(bn2_v[o2 + 16] + BN_EPS);
        const float btB = bn2_b[o2 + 16] - bn2_m[o2 + 16] * ivB;
#pragma unroll
        for (int j = 0; j < 13; ++j) {
            const int k = 4 * j + kq;
            if (k < K2D) {
                bw[k * 36 + o2]      = fmaxf(accA[j] * ivA + btA, 0.f);
                bw[k * 36 + o2 + 16] = fmaxf(accB[j] * ivB + btB, 0.f);
            }
        }
    }
    wave_fence();

    // ---- phase 3: logits[h][k] = cw2_b[h] + sum_o cw2[h][o] * y2[k][o]
#pragma unroll
    for (int q = 0; q < 8; ++q) {
        rA[q] = *(const float4*)(cw2 + o2 * C_R + q * 4);
        rB[q] = *(const float4*)(cw2 + (o2 + 16) * C_R + q * 4);
    }
    {
        const float bsA = cw2_b[o2], bsB = cw2_b[o2 + 16];
#pragma unroll
        for (int j = 0; j < 13; ++j) { accA[j] = bsA; accB[j] = bsB; }
    }
#pragma unroll
    for (int j = 0; j < 13; ++j) {
        const int k = 4 * j + kq;
        if (k < K2D) {
#pragma unroll
            for (int q = 0; q < 8; ++q) {
                const float4 t = *(const float4*)&bw[k * 36 + q * 4];
                accA[j] += rA[q].x*t.x + rA[q].y*t.y + rA[q].z*t.z + rA[q].w*t.w;
                accB[j] += rB[q].x*t.x + rB[q].y*t.y + rB[q].z*t.z + rB[q].w*t.w;
            }
        }
    }
    wave_fence();

    // ---- phase 4: softmax over k per head; k is split across kq lanes + j regs
    {
        float mA = -1e30f, mB = -1e30f;
#pragma unroll
        for (int j = 0; j < 13; ++j) {
            const int k = 4 * j + kq;
            if (k < K2D) { mA = fmaxf(mA, accA[j]); mB = fmaxf(mB, accB[j]); }
        }
        mA = fmaxf(mA, __shfl_xor(mA, 16, 64));
        mA = fmaxf(mA, __shfl_xor(mA, 32, 64));
        mB = fmaxf(mB, __shfl_xor(mB, 16, 64));
        mB = fmaxf(mB, __shfl_xor(mB, 32, 64));
        float sA = 0.f, sB = 0.f;
#pragma unroll
        for (int j = 0; j < 13; ++j) {
            const int k = 4 * j + kq;
            if (k < K2D) {
                accA[j] = __expf(accA[j] - mA); sA += accA[j];
                accB[j] = __expf(accB[j] - mB); sB += accB[j];
            }
        }
        sA += __shfl_xor(sA, 16, 64); sA += __shfl_xor(sA, 32, 64);
        sB += __shfl_xor(sB, 16, 64); sB += __shfl_xor(sB, 32, 64);
        const float rsA = 1.f / sA, rsB = 1.f / sB;
#pragma unroll
        for (int j = 0; j < 13; ++j) {
            const int k = 4 * j + kq;
            if (k < K2D) {
                bw[k * 36 + o2]      = accA[j] * rsA;
                bw[k * 36 + o2 + 16] = accB[j] * rsB;
            }
        }
    }
    wave_fence();

    // ---- phase 5: out[c] = sum_k x3[pk[k]][c] * wgt[k][c>>3]; c = 4*lane..+3
    {
        const int hn = lane >> 1;     // (4*lane)/8
        float4 a = make_float4(0.f, 0.f, 0.f, 0.f);
        for (int k = 0; k < K2D; ++k) {
            const int rp = pk[w][k];
            const float wv = bw[k * 36 + hn];
            const float4 v = *(const float4*)(base + (size_t)rp * C_ALL + 64 + lane * 4);
            a.x += v.x * wv; a.y += v.y * wv; a.z += v.z * wv; a.w += v.w * wv;
        }
        *(float4*)(outt + ((size_t)b * HW_N + pos) * C_OUT + lane * 4) = a;
    }
}

// ---------------------------------------------------------------------------
// Kernel 3: transpose [b][i][c] -> [b][c][i]
// ---------------------------------------------------------------------------
__global__ __launch_bounds__(256) void k_transpose(
    const float* __restrict__ in, float* __restrict__ out)
{
    __shared__ float ts[32][33];
    const int tid = threadIdx.x;
    const int b  = blockIdx.z;
    const int i0 = blockIdx.x * 32;
    const int c0 = blockIdx.y * 32;
    const int rr = tid >> 5, cc = tid & 31;
#pragma unroll
    for (int r = 0; r < 4; ++r) {
        const int ii = rr * 4 + r;
        ts[ii][cc] = in[((size_t)b * HW_N + i0 + ii) * C_OUT + c0 + cc];
    }
    __syncthreads();
#pragma unroll
    for (int r = 0; r < 4; ++r) {
        const int ccl = rr * 4 + r;
        out[((size_t)b * C_OUT + c0 + ccl) * HW_N + i0 + cc] = ts[cc][ccl];
    }
}

// ---------------------------------------------------------------------------
extern "C" void kernel_launch(void* const* d_in, const int* in_sizes, int n_in,
                              void* d_out, int out_size, void* d_ws, size_t ws_size,
                              hipStream_t stream)
{
    const float* x     = (const float*)d_in[0];
    const float* w1c   = (const float*)d_in[1];
    const float* b1c   = (const float*)d_in[2];
    const float* w2c   = (const float*)d_in[3];
    const float* b2c   = (const float*)d_in[4];
    const float* w3c   = (const float*)d_in[5];
    const float* b3c   = (const float*)d_in[6];
    const float* bn1_g = (const float*)d_in[7];
    const float* bn1_b = (const float*)d_in[8];
    const float* bn1_m = (const float*)d_in[9];
    const float* bn1_v = (const float*)d_in[10];
    const float* cw1   = (const float*)d_in[11];
    const float* bn2_g = (const float*)d_in[12];
    const float* bn2_b = (const float*)d_in[13];
    const float* bn2_m = (const float*)d_in[14];
    const float* bn2_v = (const float*)d_in[15];
    const float* cw2   = (const float*)d_in[16];
    const float* cw2_b = (const float*)d_in[17];

    float* xall = (float*)d_ws;                              // [4][3136][320]
    float* outt = xall + (size_t)4 * HW_N * C_ALL;           // [4][3136][256]

    k_conv<<<dim3(49, 5, 4), 256, 0, stream>>>(x, w1c, b1c, w2c, b2c, w3c, b3c, xall);
    k_attn<<<dim3(784, 4, 1), 256, 0, stream>>>(xall,
        bn1_g, bn1_b, bn1_m, bn1_v, cw1,
        bn2_g, bn2_b, bn2_m, bn2_v, cw2, cw2_b, outt);
    k_transpose<<<dim3(98, 8, 4), 256, 0, stream>>>(outt, (float*)d_out);
}

// Round 4
// 237.851 us; speedup vs baseline: 1.3246x; 1.2347x over previous
//
#include <hip/hip_runtime.h>
#include <math.h>

#define HW_N   3136
#define W_DIM  56
#define C_IN   256
#define C_R    32
#define C_OUT  256
#define C_ALL  320
#define K2D    49
#define RS     40        // t-row stride in halfs (80 B, 16B-aligned)
#define BN_EPS 1e-5f

typedef _Float16 h2 __attribute__((ext_vector_type(2)));
typedef _Float16 h8 __attribute__((ext_vector_type(8)));
typedef __fp16  g2 __attribute__((ext_vector_type(2)));   // cvt_pkrtz return type

__device__ __forceinline__ h2 pkrtz(float a, float b) {
    g2 r = __builtin_amdgcn_cvt_pkrtz(a, b);
    return __builtin_bit_cast(h2, r);
}

__device__ __forceinline__ int refl(int v) {
    v = (v < 0) ? -v : v;
    return (v > 55) ? (110 - v) : v;
}

__device__ __forceinline__ float fdot2(h2 a, h2 b, float c) {
#if __has_builtin(__builtin_amdgcn_fdot2)
    return __builtin_amdgcn_fdot2(a, b, c, false);
#else
    return c + (float)a[0] * (float)b[0] + (float)a[1] * (float)b[1];
#endif
}

// Wave-local "barrier": buf[w]/pk[w] are wave-private; DS pipe is in-order
// per wave, so we only need the compiler fence + lgkmcnt drain.
__device__ __forceinline__ void wave_fence() {
    asm volatile("s_waitcnt lgkmcnt(0)" ::: "memory");
}

// ---------------------------------------------------------------------------
// Kernel 1: fused conv1x1 for x1|x2|x3 -> xall[b][pos][320]
// ---------------------------------------------------------------------------
__global__ __launch_bounds__(256) void k_conv(
    const float* __restrict__ x,
    const float* __restrict__ w1c, const float* __restrict__ b1c,
    const float* __restrict__ w2c, const float* __restrict__ b2c,
    const float* __restrict__ w3c, const float* __restrict__ b3c,
    float* __restrict__ xall)
{
    __shared__ __align__(16) float xs[64][68];
    __shared__ __align__(16) float wl[64][68];
    const int tid  = threadIdx.x;
    const int b    = blockIdx.z;
    const int cot  = blockIdx.y;          // 0..4  (co tile of 64)
    const int pos0 = blockIdx.x * 64;     // pos tile

    const int lr  = tid >> 4;             // 0..15
    const int lc4 = (tid & 15) * 4;       // 0..60 step 4
    const int co0 = (tid >> 4) * 4;       // 0..60 step 4
    const int pp0 = (tid & 15) * 4;       // 0..60 step 4

    float acc[4][4];
#pragma unroll
    for (int j = 0; j < 4; ++j)
#pragma unroll
        for (int p = 0; p < 4; ++p) acc[j][p] = 0.f;

    for (int ch = 0; ch < 4; ++ch) {
        const int cib = ch * 64;
#pragma unroll
        for (int r = 0; r < 4; ++r) {
            const int ci = lr + 16 * r;
            *(float4*)&xs[ci][lc4] =
                *(const float4*)(x + ((size_t)b * C_IN + cib + ci) * HW_N + pos0 + lc4);
        }
#pragma unroll
        for (int r = 0; r < 4; ++r) {
            const int col = lr + 16 * r;
            const int cog = cot * 64 + col;
            const float* wp = (cog < 32) ? (w1c + cog * C_IN)
                            : (cog < 64) ? (w2c + (cog - 32) * C_IN)
                                         : (w3c + (cog - 64) * C_IN);
            *(float4*)&wl[col][lc4] = *(const float4*)(wp + cib + lc4);
        }
        __syncthreads();
#pragma unroll
        for (int c4 = 0; c4 < 16; ++c4) {
            const int ci = c4 * 4;
            const float4 a0 = *(const float4*)&wl[co0 + 0][ci];
            const float4 a1 = *(const float4*)&wl[co0 + 1][ci];
            const float4 a2 = *(const float4*)&wl[co0 + 2][ci];
            const float4 a3 = *(const float4*)&wl[co0 + 3][ci];
            const float4 b0 = *(const float4*)&xs[ci + 0][pp0];
            const float4 b1 = *(const float4*)&xs[ci + 1][pp0];
            const float4 b2 = *(const float4*)&xs[ci + 2][pp0];
            const float4 b3 = *(const float4*)&xs[ci + 3][pp0];
#define FMA_ROW(AJ, J)                                                   \
            acc[J][0] += AJ.x*b0.x + AJ.y*b1.x + AJ.z*b2.x + AJ.w*b3.x;  \
            acc[J][1] += AJ.x*b0.y + AJ.y*b1.y + AJ.z*b2.y + AJ.w*b3.y;  \
            acc[J][2] += AJ.x*b0.z + AJ.y*b1.z + AJ.z*b2.z + AJ.w*b3.z;  \
            acc[J][3] += AJ.x*b0.w + AJ.y*b1.w + AJ.z*b2.w + AJ.w*b3.w;
            FMA_ROW(a0, 0) FMA_ROW(a1, 1) FMA_ROW(a2, 2) FMA_ROW(a3, 3)
#undef FMA_ROW
        }
        __syncthreads();
    }

#pragma unroll
    for (int j = 0; j < 4; ++j) {
        const int cog = cot * 64 + co0 + j;
        const float bias = (cog < 32) ? b1c[cog] : (cog < 64) ? b2c[cog - 32] : b3c[cog - 64];
#pragma unroll
        for (int p = 0; p < 4; ++p) xs[pp0 + p][co0 + j] = acc[j][p] + bias;
    }
    __syncthreads();
    const int pl = tid >> 2;
#pragma unroll
    for (int r = 0; r < 4; ++r) {
        const int col = (tid & 3) * 4 + 16 * r;
        *(float4*)(xall + ((size_t)b * HW_N + pos0 + pl) * C_ALL + cot * 64 + col) =
            *(const float4*)&xs[pl][col];
    }
}

// ---------------------------------------------------------------------------
// Kernel 2: fused attention. One wave per pixel, 4 waves/block, no barriers.
// t / y2 / wgt tiles held in LDS as f16; GEMVs use v_dot2_f32_f16.
// ---------------------------------------------------------------------------
__global__ __launch_bounds__(256) void k_attn(
    const float* __restrict__ xall,
    const float* __restrict__ bn1_g, const float* __restrict__ bn1_b,
    const float* __restrict__ bn1_m, const float* __restrict__ bn1_v,
    const float* __restrict__ cw1,
    const float* __restrict__ bn2_g, const float* __restrict__ bn2_b,
    const float* __restrict__ bn2_m, const float* __restrict__ bn2_v,
    const float* __restrict__ cw2, const float* __restrict__ cw2_b,
    float* __restrict__ outt)
{
    __shared__ __align__(16) _Float16 tbuf[4][K2D * RS];
    __shared__ int pk[4][52];
    const int tid = threadIdx.x;
    const int w = tid >> 6, lane = tid & 63;
    const int b = blockIdx.y;
    const int bid  = blockIdx.x;                 // 0..783
    const int posb = (bid & 7) * 98 + (bid >> 3);   // XCD-contiguous spans
    const int pos  = posb * 4 + w;
    const int y0 = pos / W_DIM, x0 = pos - y0 * W_DIM;
    const float* __restrict__ base = xall + (size_t)b * HW_N * C_ALL;
    _Float16* tb = tbuf[w];

    // ---- phase 1: t[k][c] = relu(bn1(x1[c] - x2[pk(k)][c])), f16-packed
    {
        const int c2 = lane & 15;        // channel pair
        const int kh = lane >> 4;        // k mod 4 group
        const float2 g = *(const float2*)(bn1_g + 2 * c2);
        const float2 bb = *(const float2*)(bn1_b + 2 * c2);
        const float2 m = *(const float2*)(bn1_m + 2 * c2);
        const float2 v = *(const float2*)(bn1_v + 2 * c2);
        const float iv0 = g.x * rsqrtf(v.x + BN_EPS), bt0 = bb.x - m.x * iv0;
        const float iv1 = g.y * rsqrtf(v.y + BN_EPS), bt1 = bb.y - m.y * iv1;
        const float2 x1v = *(const float2*)(base + (size_t)pos * C_ALL + 2 * c2);
#pragma unroll
        for (int j = 0; j < 13; ++j) {
            const int k = 4 * j + kh;
            if (k < K2D) {
                const int dy = k / 7, dx = k - dy * 7;
                const int rp = refl(y0 + dy - 3) * W_DIM + refl(x0 + dx - 3);
                if (c2 == 0) pk[w][k] = rp;
                const float2 x2v = *(const float2*)(base + (size_t)rp * C_ALL + 32 + 2 * c2);
                const float t0 = fmaxf((x1v.x - x2v.x) * iv0 + bt0, 0.f);
                const float t1 = fmaxf((x1v.y - x2v.y) * iv1 + bt1, 0.f);
                *(h2*)&tb[k * RS + 2 * c2] = pkrtz(t0, t1);
            }
        }
    }
    wave_fence();

    const int o2 = lane & 15, kq = lane >> 4;   // lane = kq*16 + o2
    h2 wA[16], wB[16];
    float accA[13], accB[13];

    // ---- phase 2: y1[o][k] = sum_c cw1[o][c] * t[k][c]   (o in {o2, o2+16})
#pragma unroll
    for (int q = 0; q < 8; ++q) {
        const float4 a = *(const float4*)(cw1 + o2 * C_R + q * 4);
        const float4 c = *(const float4*)(cw1 + (o2 + 16) * C_R + q * 4);
        wA[2 * q]     = pkrtz(a.x, a.y);
        wA[2 * q + 1] = pkrtz(a.z, a.w);
        wB[2 * q]     = pkrtz(c.x, c.y);
        wB[2 * q + 1] = pkrtz(c.z, c.w);
    }
#pragma unroll
    for (int j = 0; j < 13; ++j) { accA[j] = 0.f; accB[j] = 0.f; }
#pragma unroll
    for (int j = 0; j < 13; ++j) {
        const int k = 4 * j + kq;
        if (k < K2D) {
            const _Float16* row = &tb[k * RS];
#pragma unroll
            for (int q = 0; q < 4; ++q) {
                union { h8 v; h2 p[4]; } u;
                u.v = *(const h8*)(row + q * 8);
#pragma unroll
                for (int r = 0; r < 4; ++r) {
                    accA[j] = fdot2(u.p[r], wA[4 * q + r], accA[j]);
                    accB[j] = fdot2(u.p[r], wB[4 * q + r], accB[j]);
                }
            }
        }
    }
    wave_fence();
    // bn2 + relu, write y2[k][o] (f16)
    {
        const float ivA = bn2_g[o2] * rsqrtf(bn2_v[o2] + BN_EPS);
        const float btA = bn2_b[o2] - bn2_m[o2] * ivA;
        const float ivB = bn2_g[o2 + 16] * rsqrtf(bn2_v[o2 + 16] + BN_EPS);
        const float btB = bn2_b[o2 + 16] - bn2_m[o2 + 16] * ivB;
#pragma unroll
        for (int j = 0; j < 13; ++j) {
            const int k = 4 * j + kq;
            if (k < K2D) {
                tb[k * RS + o2]      = (_Float16)fmaxf(accA[j] * ivA + btA, 0.f);
                tb[k * RS + o2 + 16] = (_Float16)fmaxf(accB[j] * ivB + btB, 0.f);
            }
        }
    }
    wave_fence();

    // ---- phase 3: logits[h][k] = cw2_b[h] + sum_o cw2[h][o] * y2[k][o]
#pragma unroll
    for (int q = 0; q < 8; ++q) {
        const float4 a = *(const float4*)(cw2 + o2 * C_R + q * 4);
        const float4 c = *(const float4*)(cw2 + (o2 + 16) * C_R + q * 4);
        wA[2 * q]     = pkrtz(a.x, a.y);
        wA[2 * q + 1] = pkrtz(a.z, a.w);
        wB[2 * q]     = pkrtz(c.x, c.y);
        wB[2 * q + 1] = pkrtz(c.z, c.w);
    }
    {
        const float bsA = cw2_b[o2], bsB = cw2_b[o2 + 16];
#pragma unroll
        for (int j = 0; j < 13; ++j) { accA[j] = bsA; accB[j] = bsB; }
    }
#pragma unroll
    for (int j = 0; j < 13; ++j) {
        const int k = 4 * j + kq;
        if (k < K2D) {
            const _Float16* row = &tb[k * RS];
#pragma unroll
            for (int q = 0; q < 4; ++q) {
                union { h8 v; h2 p[4]; } u;
                u.v = *(const h8*)(row + q * 8);
#pragma unroll
                for (int r = 0; r < 4; ++r) {
                    accA[j] = fdot2(u.p[r], wA[4 * q + r], accA[j]);
                    accB[j] = fdot2(u.p[r], wB[4 * q + r], accB[j]);
                }
            }
        }
    }
    wave_fence();

    // ---- phase 4: softmax over k per head; wgt stored f16
    {
        float mA = -1e30f, mB = -1e30f;
#pragma unroll
        for (int j = 0; j < 13; ++j) {
            const int k = 4 * j + kq;
            if (k < K2D) { mA = fmaxf(mA, accA[j]); mB = fmaxf(mB, accB[j]); }
        }
        mA = fmaxf(mA, __shfl_xor(mA, 16, 64));
        mA = fmaxf(mA, __shfl_xor(mA, 32, 64));
        mB = fmaxf(mB, __shfl_xor(mB, 16, 64));
        mB = fmaxf(mB, __shfl_xor(mB, 32, 64));
        float sA = 0.f, sB = 0.f;
#pragma unroll
        for (int j = 0; j < 13; ++j) {
            const int k = 4 * j + kq;
            if (k < K2D) {
                accA[j] = __expf(accA[j] - mA); sA += accA[j];
                accB[j] = __expf(accB[j] - mB); sB += accB[j];
            }
        }
        sA += __shfl_xor(sA, 16, 64); sA += __shfl_xor(sA, 32, 64);
        sB += __shfl_xor(sB, 16, 64); sB += __shfl_xor(sB, 32, 64);
        const float rsA = 1.f / sA, rsB = 1.f / sB;
#pragma unroll
        for (int j = 0; j < 13; ++j) {
            const int k = 4 * j + kq;
            if (k < K2D) {
                tb[k * RS + o2]      = (_Float16)(accA[j] * rsA);
                tb[k * RS + o2 + 16] = (_Float16)(accB[j] * rsB);
            }
        }
    }
    wave_fence();

    // ---- phase 5: out[c] = sum_k x3[pk[k]][c] * wgt[k][c>>3]; c = 4*lane..+3
    {
        const int hn = lane >> 1;     // (4*lane)/8
        float4 a = make_float4(0.f, 0.f, 0.f, 0.f);
#pragma unroll 7
        for (int k = 0; k < K2D; ++k) {
            const int rp = pk[w][k];
            const float wv = (float)tb[k * RS + hn];
            const float4 v = *(const float4*)(base + (size_t)rp * C_ALL + 64 + lane * 4);
            a.x += v.x * wv; a.y += v.y * wv; a.z += v.z * wv; a.w += v.w * wv;
        }
        *(float4*)(outt + ((size_t)b * HW_N + pos) * C_OUT + lane * 4) = a;
    }
}

// ---------------------------------------------------------------------------
// Kernel 3: transpose [b][i][c] -> [b][c][i]
// ---------------------------------------------------------------------------
__global__ __launch_bounds__(256) void k_transpose(
    const float* __restrict__ in, float* __restrict__ out)
{
    __shared__ float ts[32][33];
    const int tid = threadIdx.x;
    const int b  = blockIdx.z;
    const int i0 = blockIdx.x * 32;
    const int c0 = blockIdx.y * 32;
    const int rr = tid >> 5, cc = tid & 31;
#pragma unroll
    for (int r = 0; r < 4; ++r) {
        const int ii = rr * 4 + r;
        ts[ii][cc] = in[((size_t)b * HW_N + i0 + ii) * C_OUT + c0 + cc];
    }
    __syncthreads();
#pragma unroll
    for (int r = 0; r < 4; ++r) {
        const int ccl = rr * 4 + r;
        out[((size_t)b * C_OUT + c0 + ccl) * HW_N + i0 + cc] = ts[cc][ccl];
    }
}

// ---------------------------------------------------------------------------
extern "C" void kernel_launch(void* const* d_in, const int* in_sizes, int n_in,
                              void* d_out, int out_size, void* d_ws, size_t ws_size,
                              hipStream_t stream)
{
    const float* x     = (const float*)d_in[0];
    const float* w1c   = (const float*)d_in[1];
    const float* b1c   = (const float*)d_in[2];
    const float* w2c   = (const float*)d_in[3];
    const float* b2c   = (const float*)d_in[4];
    const float* w3c   = (const float*)d_in[5];
    const float* b3c   = (const float*)d_in[6];
    const float* bn1_g = (const float*)d_in[7];
    const float* bn1_b = (const float*)d_in[8];
    const float* bn1_m = (const float*)d_in[9];
    const float* bn1_v = (const float*)d_in[10];
    const float* cw1   = (const float*)d_in[11];
    const float* bn2_g = (const float*)d_in[12];
    const float* bn2_b = (const float*)d_in[13];
    const float* bn2_m = (const float*)d_in[14];
    const float* bn2_v = (const float*)d_in[15];
    const float* cw2   = (const float*)d_in[16];
    const float* cw2_b = (const float*)d_in[17];

    float* xall = (float*)d_ws;                              // [4][3136][320]
    float* outt = xall + (size_t)4 * HW_N * C_ALL;           // [4][3136][256]

    k_conv<<<dim3(49, 5, 4), 256, 0, stream>>>(x, w1c, b1c, w2c, b2c, w3c, b3c, xall);
    k_attn<<<dim3(784, 4, 1), 256, 0, stream>>>(xall,
        bn1_g, bn1_b, bn1_m, bn1_v, cw1,
        bn2_g, bn2_b, bn2_m, bn2_v, cw2, cw2_b, outt);
    k_transpose<<<dim3(98, 8, 4), 256, 0, stream>>>(outt, (float*)d_out);
}

// Round 5
// 210.255 us; speedup vs baseline: 1.4985x; 1.1313x over previous
//
#include <hip/hip_runtime.h>
#include <math.h>

#define HW_N   3136
#define W_DIM  56
#define C_IN   256
#define C_R    32
#define C_OUT  256
#define C_ALL  320
#define K2D    49
#define RS     40        // attn t-row stride in halfs (80 B, 16B-aligned)
#define BN_EPS 1e-5f

typedef _Float16 h2 __attribute__((ext_vector_type(2)));
typedef _Float16 h8 __attribute__((ext_vector_type(8)));
typedef __fp16  g2 __attribute__((ext_vector_type(2)));   // cvt_pkrtz return type
typedef __fp16  g4 __attribute__((ext_vector_type(4)));
typedef __fp16  g8 __attribute__((ext_vector_type(8)));
typedef float   f4 __attribute__((ext_vector_type(4)));

__device__ __forceinline__ h2 pkrtz(float a, float b) {
    g2 r = __builtin_amdgcn_cvt_pkrtz(a, b);
    return __builtin_bit_cast(h2, r);
}

__device__ __forceinline__ int refl(int v) {
    v = (v < 0) ? -v : v;
    return (v > 55) ? (110 - v) : v;
}

__device__ __forceinline__ float fdot2(h2 a, h2 b, float c) {
#if __has_builtin(__builtin_amdgcn_fdot2)
    return __builtin_amdgcn_fdot2(a, b, c, false);
#else
    return c + (float)a[0] * (float)b[0] + (float)a[1] * (float)b[1];
#endif
}

// Wave-local "barrier": buf[w]/pk[w] are wave-private; DS pipe is in-order
// per wave, so we only need the compiler fence + lgkmcnt drain.
__device__ __forceinline__ void wave_fence() {
    asm volatile("s_waitcnt lgkmcnt(0)" ::: "memory");
}

// ---------------------------------------------------------------------------
// Kernel 0a: pack weights w1c|w2c|w3c -> wh[320][256] f16
// ---------------------------------------------------------------------------
__global__ __launch_bounds__(256) void k_prep_w(
    const float* __restrict__ w1c, const float* __restrict__ w2c,
    const float* __restrict__ w3c, __fp16* __restrict__ wh)
{
    const int idx = blockIdx.x * 256 + threadIdx.x;   // 0..20479
    const int r  = idx >> 6;
    const int c4 = (idx & 63) * 4;
    const float* wp = (r < 32) ? (w1c + r * C_IN)
                    : (r < 64) ? (w2c + (r - 32) * C_IN)
                               : (w3c + (r - 64) * C_IN);
    const float4 wv = *(const float4*)(wp + c4);
    const g2 lo = __builtin_amdgcn_cvt_pkrtz(wv.x, wv.y);
    const g2 hi = __builtin_amdgcn_cvt_pkrtz(wv.z, wv.w);
    g4 o; o[0] = lo[0]; o[1] = lo[1]; o[2] = hi[0]; o[3] = hi[1];
    *(g4*)(wh + (size_t)r * C_IN + c4) = o;
}

// ---------------------------------------------------------------------------
// Kernel 0b: transpose+convert x[b][ci][pos] f32 -> xT16[b][pos][ci] f16.
// Each thread: one pos, 32 ci (one full 64B output line). Reads coalesced
// along pos (lane = pos).
// ---------------------------------------------------------------------------
__global__ __launch_bounds__(256) void k_prep_x(
    const float* __restrict__ x, __fp16* __restrict__ xT16)
{
    const int t   = threadIdx.x;
    const int b   = blockIdx.z;
    const int pos = blockIdx.x * 64 + (t & 63);
    const int ci0 = (blockIdx.y * 4 + (t >> 6)) * 32;
    const float* __restrict__ xp = x + ((size_t)b * C_IN + ci0) * HW_N + pos;
    float v[32];
#pragma unroll
    for (int j = 0; j < 32; ++j) v[j] = xp[(size_t)j * HW_N];
    __fp16* op = xT16 + ((size_t)b * HW_N + pos) * C_IN + ci0;
#pragma unroll
    for (int q = 0; q < 4; ++q) {
        g8 o;
#pragma unroll
        for (int i = 0; i < 4; ++i) {
            const g2 p = __builtin_amdgcn_cvt_pkrtz(v[q * 8 + 2 * i], v[q * 8 + 2 * i + 1]);
            o[2 * i] = p[0]; o[2 * i + 1] = p[1];
        }
        *(g8*)(op + q * 8) = o;
    }
}

// ---------------------------------------------------------------------------
// Kernel 1: MFMA conv1x1. xall[b][pos][320] = xT16[b][pos][:] . wh[co][:]^T
// 64 pos x 64 co per block; wave w owns co sub-tile 16w; no LDS, A/B frags
// loaded straight from global (L2-hot). 8 K-steps of 16x16x32 f16 MFMA.
// ---------------------------------------------------------------------------
__global__ __launch_bounds__(256) void k_conv_mfma(
    const __fp16* __restrict__ xT16, const __fp16* __restrict__ wh,
    const float* __restrict__ b1c, const float* __restrict__ b2c,
    const float* __restrict__ b3c, float* __restrict__ xall)
{
    const int t = threadIdx.x, w = t >> 6, lane = t & 63;
    const int quad = lane >> 4, l16 = lane & 15;
    const int b = blockIdx.z, pos0 = blockIdx.x * 64, co0 = blockIdx.y * 64;
    const int co_row = co0 + w * 16 + l16;

    const __fp16* arow = xT16 + ((size_t)b * HW_N + pos0 + l16) * C_IN + quad * 8;
    const __fp16* brow = wh + (size_t)co_row * C_IN + quad * 8;

    f4 acc[4];
#pragma unroll
    for (int mt = 0; mt < 4; ++mt) acc[mt] = (f4){0.f, 0.f, 0.f, 0.f};

#pragma unroll
    for (int ks = 0; ks < 8; ++ks) {
        const g8 bf = *(const g8*)(brow + ks * 32);
#pragma unroll
        for (int mt = 0; mt < 4; ++mt) {
            const g8 af = *(const g8*)(arow + (size_t)mt * 16 * C_IN + ks * 32);
            acc[mt] = __builtin_amdgcn_mfma_f32_16x16x32_f16(af, bf, acc[mt], 0, 0, 0);
        }
    }

    const float bias = (co_row < 32) ? b1c[co_row]
                     : (co_row < 64) ? b2c[co_row - 32] : b3c[co_row - 64];
#pragma unroll
    for (int mt = 0; mt < 4; ++mt) {
#pragma unroll
        for (int r = 0; r < 4; ++r) {
            const int pos_w = pos0 + mt * 16 + quad * 4 + r;
            xall[((size_t)b * HW_N + pos_w) * C_ALL + co_row] = acc[mt][r] + bias;
        }
    }
}

// ---------------------------------------------------------------------------
// Kernel 2: fused attention. One wave per pixel, 4 waves/block, no barriers.
// t / y2 / wgt tiles held in LDS as f16; GEMVs use v_dot2_f32_f16.
// ---------------------------------------------------------------------------
__global__ __launch_bounds__(256) void k_attn(
    const float* __restrict__ xall,
    const float* __restrict__ bn1_g, const float* __restrict__ bn1_b,
    const float* __restrict__ bn1_m, const float* __restrict__ bn1_v,
    const float* __restrict__ cw1,
    const float* __restrict__ bn2_g, const float* __restrict__ bn2_b,
    const float* __restrict__ bn2_m, const float* __restrict__ bn2_v,
    const float* __restrict__ cw2, const float* __restrict__ cw2_b,
    float* __restrict__ outt)
{
    __shared__ __align__(16) _Float16 tbuf[4][K2D * RS];
    __shared__ int pk[4][52];
    const int tid = threadIdx.x;
    const int w = tid >> 6, lane = tid & 63;
    const int b = blockIdx.y;
    const int bid  = blockIdx.x;                 // 0..783
    const int posb = (bid & 7) * 98 + (bid >> 3);   // XCD-contiguous spans
    const int pos  = posb * 4 + w;
    const int y0 = pos / W_DIM, x0 = pos - y0 * W_DIM;
    const float* __restrict__ base = xall + (size_t)b * HW_N * C_ALL;
    _Float16* tb = tbuf[w];

    // ---- phase 1: t[k][c] = relu(bn1(x1[c] - x2[pk(k)][c])), f16-packed
    {
        const int c2 = lane & 15;        // channel pair
        const int kh = lane >> 4;        // k mod 4 group
        const float2 g = *(const float2*)(bn1_g + 2 * c2);
        const float2 bb = *(const float2*)(bn1_b + 2 * c2);
        const float2 m = *(const float2*)(bn1_m + 2 * c2);
        const float2 v = *(const float2*)(bn1_v + 2 * c2);
        const float iv0 = g.x * rsqrtf(v.x + BN_EPS), bt0 = bb.x - m.x * iv0;
        const float iv1 = g.y * rsqrtf(v.y + BN_EPS), bt1 = bb.y - m.y * iv1;
        const float2 x1v = *(const float2*)(base + (size_t)pos * C_ALL + 2 * c2);
#pragma unroll
        for (int j = 0; j < 13; ++j) {
            const int k = 4 * j + kh;
            if (k < K2D) {
                const int dy = k / 7, dx = k - dy * 7;
                const int rp = refl(y0 + dy - 3) * W_DIM + refl(x0 + dx - 3);
                if (c2 == 0) pk[w][k] = rp;
                const float2 x2v = *(const float2*)(base + (size_t)rp * C_ALL + 32 + 2 * c2);
                const float t0 = fmaxf((x1v.x - x2v.x) * iv0 + bt0, 0.f);
                const float t1 = fmaxf((x1v.y - x2v.y) * iv1 + bt1, 0.f);
                *(h2*)&tb[k * RS + 2 * c2] = pkrtz(t0, t1);
            }
        }
    }
    wave_fence();

    const int o2 = lane & 15, kq = lane >> 4;   // lane = kq*16 + o2
    h2 wA[16], wB[16];
    float accA[13], accB[13];

    // ---- phase 2: y1[o][k] = sum_c cw1[o][c] * t[k][c]   (o in {o2, o2+16})
#pragma unroll
    for (int q = 0; q < 8; ++q) {
        const float4 a = *(const float4*)(cw1 + o2 * C_R + q * 4);
        const float4 c = *(const float4*)(cw1 + (o2 + 16) * C_R + q * 4);
        wA[2 * q]     = pkrtz(a.x, a.y);
        wA[2 * q + 1] = pkrtz(a.z, a.w);
        wB[2 * q]     = pkrtz(c.x, c.y);
        wB[2 * q + 1] = pkrtz(c.z, c.w);
    }
#pragma unroll
    for (int j = 0; j < 13; ++j) { accA[j] = 0.f; accB[j] = 0.f; }
#pragma unroll
    for (int j = 0; j < 13; ++j) {
        const int k = 4 * j + kq;
        if (k < K2D) {
            const _Float16* row = &tb[k * RS];
#pragma unroll
            for (int q = 0; q < 4; ++q) {
                union { h8 v; h2 p[4]; } u;
                u.v = *(const h8*)(row + q * 8);
#pragma unroll
                for (int r = 0; r < 4; ++r) {
                    accA[j] = fdot2(u.p[r], wA[4 * q + r], accA[j]);
                    accB[j] = fdot2(u.p[r], wB[4 * q + r], accB[j]);
                }
            }
        }
    }
    wave_fence();
    // bn2 + relu, write y2[k][o] (f16)
    {
        const float ivA = bn2_g[o2] * rsqrtf(bn2_v[o2] + BN_EPS);
        const float btA = bn2_b[o2] - bn2_m[o2] * ivA;
        const float ivB = bn2_g[o2 + 16] * rsqrtf(bn2_v[o2 + 16] + BN_EPS);
        const float btB = bn2_b[o2 + 16] - bn2_m[o2 + 16] * ivB;
#pragma unroll
        for (int j = 0; j < 13; ++j) {
            const int k = 4 * j + kq;
            if (k < K2D) {
                tb[k * RS + o2]      = (_Float16)fmaxf(accA[j] * ivA + btA, 0.f);
                tb[k * RS + o2 + 16] = (_Float16)fmaxf(accB[j] * ivB + btB, 0.f);
            }
        }
    }
    wave_fence();

    // ---- phase 3: logits[h][k] = cw2_b[h] + sum_o cw2[h][o] * y2[k][o]
#pragma unroll
    for (int q = 0; q < 8; ++q) {
        const float4 a = *(const float4*)(cw2 + o2 * C_R + q * 4);
        const float4 c = *(const float4*)(cw2 + (o2 + 16) * C_R + q * 4);
        wA[2 * q]     = pkrtz(a.x, a.y);
        wA[2 * q + 1] = pkrtz(a.z, a.w);
        wB[2 * q]     = pkrtz(c.x, c.y);
        wB[2 * q + 1] = pkrtz(c.z, c.w);
    }
    {
        const float bsA = cw2_b[o2], bsB = cw2_b[o2 + 16];
#pragma unroll
        for (int j = 0; j < 13; ++j) { accA[j] = bsA; accB[j] = bsB; }
    }
#pragma unroll
    for (int j = 0; j < 13; ++j) {
        const int k = 4 * j + kq;
        if (k < K2D) {
            const _Float16* row = &tb[k * RS];
#pragma unroll
            for (int q = 0; q < 4; ++q) {
                union { h8 v; h2 p[4]; } u;
                u.v = *(const h8*)(row + q * 8);
#pragma unroll
                for (int r = 0; r < 4; ++r) {
                    accA[j] = fdot2(u.p[r], wA[4 * q + r], accA[j]);
                    accB[j] = fdot2(u.p[r], wB[4 * q + r], accB[j]);
                }
            }
        }
    }
    wave_fence();

    // ---- phase 4: softmax over k per head; wgt stored f16
    {
        float mA = -1e30f, mB = -1e30f;
#pragma unroll
        for (int j = 0; j < 13; ++j) {
            const int k = 4 * j + kq;
            if (k < K2D) { mA = fmaxf(mA, accA[j]); mB = fmaxf(mB, accB[j]); }
        }
        mA = fmaxf(mA, __shfl_xor(mA, 16, 64));
        mA = fmaxf(mA, __shfl_xor(mA, 32, 64));
        mB = fmaxf(mB, __shfl_xor(mB, 16, 64));
        mB = fmaxf(mB, __shfl_xor(mB, 32, 64));
        float sA = 0.f, sB = 0.f;
#pragma unroll
        for (int j = 0; j < 13; ++j) {
            const int k = 4 * j + kq;
            if (k < K2D) {
                accA[j] = __expf(accA[j] - mA); sA += accA[j];
                accB[j] = __expf(accB[j] - mB); sB += accB[j];
            }
        }
        sA += __shfl_xor(sA, 16, 64); sA += __shfl_xor(sA, 32, 64);
        sB += __shfl_xor(sB, 16, 64); sB += __shfl_xor(sB, 32, 64);
        const float rsA = 1.f / sA, rsB = 1.f / sB;
#pragma unroll
        for (int j = 0; j < 13; ++j) {
            const int k = 4 * j + kq;
            if (k < K2D) {
                tb[k * RS + o2]      = (_Float16)(accA[j] * rsA);
                tb[k * RS + o2 + 16] = (_Float16)(accB[j] * rsB);
            }
        }
    }
    wave_fence();

    // ---- phase 5: out[c] = sum_k x3[pk[k]][c] * wgt[k][c>>3]; c = 4*lane..+3
    {
        const int hn = lane >> 1;     // (4*lane)/8
        float4 a = make_float4(0.f, 0.f, 0.f, 0.f);
#pragma unroll 7
        for (int k = 0; k < K2D; ++k) {
            const int rp = pk[w][k];
            const float wv = (float)tb[k * RS + hn];
            const float4 v = *(const float4*)(base + (size_t)rp * C_ALL + 64 + lane * 4);
            a.x += v.x * wv; a.y += v.y * wv; a.z += v.z * wv; a.w += v.w * wv;
        }
        *(float4*)(outt + ((size_t)b * HW_N + pos) * C_OUT + lane * 4) = a;
    }
}

// ---------------------------------------------------------------------------
// Kernel 3: transpose [b][i][c] -> [b][c][i]
// ---------------------------------------------------------------------------
__global__ __launch_bounds__(256) void k_transpose(
    const float* __restrict__ in, float* __restrict__ out)
{
    __shared__ float ts[32][33];
    const int tid = threadIdx.x;
    const int b  = blockIdx.z;
    const int i0 = blockIdx.x * 32;
    const int c0 = blockIdx.y * 32;
    const int rr = tid >> 5, cc = tid & 31;
#pragma unroll
    for (int r = 0; r < 4; ++r) {
        const int ii = rr * 4 + r;
        ts[ii][cc] = in[((size_t)b * HW_N + i0 + ii) * C_OUT + c0 + cc];
    }
    __syncthreads();
#pragma unroll
    for (int r = 0; r < 4; ++r) {
        const int ccl = rr * 4 + r;
        out[((size_t)b * C_OUT + c0 + ccl) * HW_N + i0 + cc] = ts[cc][ccl];
    }
}

// ---------------------------------------------------------------------------
extern "C" void kernel_launch(void* const* d_in, const int* in_sizes, int n_in,
                              void* d_out, int out_size, void* d_ws, size_t ws_size,
                              hipStream_t stream)
{
    const float* x     = (const float*)d_in[0];
    const float* w1c   = (const float*)d_in[1];
    const float* b1c   = (const float*)d_in[2];
    const float* w2c   = (const float*)d_in[3];
    const float* b2c   = (const float*)d_in[4];
    const float* w3c   = (const float*)d_in[5];
    const float* b3c   = (const float*)d_in[6];
    const float* bn1_g = (const float*)d_in[7];
    const float* bn1_b = (const float*)d_in[8];
    const float* bn1_m = (const float*)d_in[9];
    const float* bn1_v = (const float*)d_in[10];
    const float* cw1   = (const float*)d_in[11];
    const float* bn2_g = (const float*)d_in[12];
    const float* bn2_b = (const float*)d_in[13];
    const float* bn2_m = (const float*)d_in[14];
    const float* bn2_v = (const float*)d_in[15];
    const float* cw2   = (const float*)d_in[16];
    const float* cw2_b = (const float*)d_in[17];

    float* xall = (float*)d_ws;                              // [4][3136][320] f32
    float* outt = xall + (size_t)4 * HW_N * C_ALL;           // [4][3136][256] f32
    // xT16/wh alias the outt region: dead before k_attn writes outt.
    __fp16* xT16 = (__fp16*)outt;                            // [4][3136][256] f16
    __fp16* wh   = xT16 + (size_t)4 * HW_N * C_IN;           // [320][256] f16

    k_prep_w<<<80, 256, 0, stream>>>(w1c, w2c, w3c, wh);
    k_prep_x<<<dim3(49, 2, 4), 256, 0, stream>>>(x, xT16);
    k_conv_mfma<<<dim3(49, 5, 4), 256, 0, stream>>>(xT16, wh, b1c, b2c, b3c, xall);
    k_attn<<<dim3(784, 4, 1), 256, 0, stream>>>(xall,
        bn1_g, bn1_b, bn1_m, bn1_v, cw1,
        bn2_g, bn2_b, bn2_m, bn2_v, cw2, cw2_b, outt);
    k_transpose<<<dim3(98, 8, 4), 256, 0, stream>>>(outt, (float*)d_out);
}

// Round 6
// 169.298 us; speedup vs baseline: 1.8610x; 1.2419x over previous
//
#include <hip/hip_runtime.h>
#include <math.h>

#define HW_N   3136
#define W_DIM  56
#define C_IN   256
#define C_R    32
#define C_OUT  256
#define C_ALL  320
#define K2D    49
#define RS     40        // attn t-row stride in halfs (80 B, 16B-aligned)
#define BN_EPS 1e-5f

typedef _Float16 h2 __attribute__((ext_vector_type(2)));
typedef __fp16  g2 __attribute__((ext_vector_type(2)));   // cvt_pkrtz return type
typedef __fp16  g4 __attribute__((ext_vector_type(4)));
typedef __fp16  g8 __attribute__((ext_vector_type(8)));
typedef float   f4 __attribute__((ext_vector_type(4)));

__device__ __forceinline__ h2 pkrtz(float a, float b) {
    g2 r = __builtin_amdgcn_cvt_pkrtz(a, b);
    return __builtin_bit_cast(h2, r);
}

__device__ __forceinline__ g8 pack8(float4 a, float4 b) {
    g2 p0 = __builtin_amdgcn_cvt_pkrtz(a.x, a.y);
    g2 p1 = __builtin_amdgcn_cvt_pkrtz(a.z, a.w);
    g2 p2 = __builtin_amdgcn_cvt_pkrtz(b.x, b.y);
    g2 p3 = __builtin_amdgcn_cvt_pkrtz(b.z, b.w);
    g8 o;
    o[0] = p0[0]; o[1] = p0[1]; o[2] = p1[0]; o[3] = p1[1];
    o[4] = p2[0]; o[5] = p2[1]; o[6] = p3[0]; o[7] = p3[1];
    return o;
}

__device__ __forceinline__ int refl(int v) {
    v = (v < 0) ? -v : v;
    return (v > 55) ? (110 - v) : v;
}

// Wave-local "barrier": buf[w]/pk[w] are wave-private; DS pipe is in-order
// per wave, so we only need the compiler fence + lgkmcnt drain.
__device__ __forceinline__ void wave_fence() {
    asm volatile("s_waitcnt lgkmcnt(0)" ::: "memory");
}

// ---------------------------------------------------------------------------
// Kernel 0a: pack weights w1c|w2c|w3c -> wh[320][256] f16
// ---------------------------------------------------------------------------
__global__ __launch_bounds__(256) void k_prep_w(
    const float* __restrict__ w1c, const float* __restrict__ w2c,
    const float* __restrict__ w3c, __fp16* __restrict__ wh)
{
    const int idx = blockIdx.x * 256 + threadIdx.x;   // 0..20479
    const int r  = idx >> 6;
    const int c4 = (idx & 63) * 4;
    const float* wp = (r < 32) ? (w1c + r * C_IN)
                    : (r < 64) ? (w2c + (r - 32) * C_IN)
                               : (w3c + (r - 64) * C_IN);
    const float4 wv = *(const float4*)(wp + c4);
    const g2 lo = __builtin_amdgcn_cvt_pkrtz(wv.x, wv.y);
    const g2 hi = __builtin_amdgcn_cvt_pkrtz(wv.z, wv.w);
    g4 o; o[0] = lo[0]; o[1] = lo[1]; o[2] = hi[0]; o[3] = hi[1];
    *(g4*)(wh + (size_t)r * C_IN + c4) = o;
}

// ---------------------------------------------------------------------------
// Kernel 0b: transpose+convert x[b][ci][pos] f32 -> xT16[b][pos][ci] f16.
// ---------------------------------------------------------------------------
__global__ __launch_bounds__(256) void k_prep_x(
    const float* __restrict__ x, __fp16* __restrict__ xT16)
{
    const int t   = threadIdx.x;
    const int b   = blockIdx.z;
    const int pos = blockIdx.x * 64 + (t & 63);
    const int ci0 = (blockIdx.y * 4 + (t >> 6)) * 32;
    const float* __restrict__ xp = x + ((size_t)b * C_IN + ci0) * HW_N + pos;
    float v[32];
#pragma unroll
    for (int j = 0; j < 32; ++j) v[j] = xp[(size_t)j * HW_N];
    __fp16* op = xT16 + ((size_t)b * HW_N + pos) * C_IN + ci0;
#pragma unroll
    for (int q = 0; q < 4; ++q) {
        g8 o;
#pragma unroll
        for (int i = 0; i < 4; ++i) {
            const g2 p = __builtin_amdgcn_cvt_pkrtz(v[q * 8 + 2 * i], v[q * 8 + 2 * i + 1]);
            o[2 * i] = p[0]; o[2 * i + 1] = p[1];
        }
        *(g8*)(op + q * 8) = o;
    }
}

// ---------------------------------------------------------------------------
// Kernel 1: MFMA conv1x1. xall[b][pos][320] = xT16[b][pos][:] . wh[co][:]^T
// ---------------------------------------------------------------------------
__global__ __launch_bounds__(256) void k_conv_mfma(
    const __fp16* __restrict__ xT16, const __fp16* __restrict__ wh,
    const float* __restrict__ b1c, const float* __restrict__ b2c,
    const float* __restrict__ b3c, float* __restrict__ xall)
{
    const int t = threadIdx.x, w = t >> 6, lane = t & 63;
    const int quad = lane >> 4, l16 = lane & 15;
    const int b = blockIdx.z, pos0 = blockIdx.x * 64, co0 = blockIdx.y * 64;
    const int co_row = co0 + w * 16 + l16;

    const __fp16* arow = xT16 + ((size_t)b * HW_N + pos0 + l16) * C_IN + quad * 8;
    const __fp16* brow = wh + (size_t)co_row * C_IN + quad * 8;

    f4 acc[4];
#pragma unroll
    for (int mt = 0; mt < 4; ++mt) acc[mt] = (f4){0.f, 0.f, 0.f, 0.f};

#pragma unroll
    for (int ks = 0; ks < 8; ++ks) {
        const g8 bf = *(const g8*)(brow + ks * 32);
#pragma unroll
        for (int mt = 0; mt < 4; ++mt) {
            const g8 af = *(const g8*)(arow + (size_t)mt * 16 * C_IN + ks * 32);
            acc[mt] = __builtin_amdgcn_mfma_f32_16x16x32_f16(af, bf, acc[mt], 0, 0, 0);
        }
    }

    const float bias = (co_row < 32) ? b1c[co_row]
                     : (co_row < 64) ? b2c[co_row - 32] : b3c[co_row - 64];
#pragma unroll
    for (int mt = 0; mt < 4; ++mt) {
#pragma unroll
        for (int r = 0; r < 4; ++r) {
            const int pos_w = pos0 + mt * 16 + quad * 4 + r;
            xall[((size_t)b * HW_N + pos_w) * C_ALL + co_row] = acc[mt][r] + bias;
        }
    }
}

// ---------------------------------------------------------------------------
// Kernel 2: fused attention. One wave per pixel, 4 waves/block, no barriers.
// t-tile padded to 64 rows; phases 2/3 run as two 64x32x32 MFMA GEMMs.
// Fragment conventions identical to k_conv_mfma (validated round 4).
// ---------------------------------------------------------------------------
__global__ __launch_bounds__(256) void k_attn(
    const float* __restrict__ xall,
    const float* __restrict__ bn1_g, const float* __restrict__ bn1_b,
    const float* __restrict__ bn1_m, const float* __restrict__ bn1_v,
    const float* __restrict__ cw1,
    const float* __restrict__ bn2_g, const float* __restrict__ bn2_b,
    const float* __restrict__ bn2_m, const float* __restrict__ bn2_v,
    const float* __restrict__ cw2, const float* __restrict__ cw2_b,
    float* __restrict__ outt)
{
    __shared__ __align__(16) _Float16 tbuf[4][64 * RS];   // 64 rows (49 valid)
    __shared__ int pk[4][52];
    const int tid = threadIdx.x;
    const int w = tid >> 6, lane = tid & 63;
    const int b = blockIdx.y;
    const int bid  = blockIdx.x;                 // 0..783
    const int posb = (bid & 7) * 98 + (bid >> 3);   // XCD-contiguous spans
    const int pos  = posb * 4 + w;
    const int y0 = pos / W_DIM, x0 = pos - y0 * W_DIM;
    const float* __restrict__ base = xall + (size_t)b * HW_N * C_ALL;
    _Float16* tb = tbuf[w];

    // ---- phase 1: t[k][c] = relu(bn1(x1[c] - x2[pk(k)][c])), f16-packed
    {
        const int c2 = lane & 15;        // channel pair
        const int kh = lane >> 4;        // k mod 4 group
        const float2 g = *(const float2*)(bn1_g + 2 * c2);
        const float2 bb = *(const float2*)(bn1_b + 2 * c2);
        const float2 m = *(const float2*)(bn1_m + 2 * c2);
        const float2 v = *(const float2*)(bn1_v + 2 * c2);
        const float iv0 = g.x * rsqrtf(v.x + BN_EPS), bt0 = bb.x - m.x * iv0;
        const float iv1 = g.y * rsqrtf(v.y + BN_EPS), bt1 = bb.y - m.y * iv1;
        const float2 x1v = *(const float2*)(base + (size_t)pos * C_ALL + 2 * c2);
#pragma unroll
        for (int j = 0; j < 13; ++j) {
            const int k = 4 * j + kh;
            if (k < K2D) {
                const int dy = k / 7, dx = k - dy * 7;
                const int rp = refl(y0 + dy - 3) * W_DIM + refl(x0 + dx - 3);
                if (c2 == 0) pk[w][k] = rp;
                const float2 x2v = *(const float2*)(base + (size_t)rp * C_ALL + 32 + 2 * c2);
                const float t0 = fmaxf((x1v.x - x2v.x) * iv0 + bt0, 0.f);
                const float t1 = fmaxf((x1v.y - x2v.y) * iv1 + bt1, 0.f);
                *(h2*)&tb[k * RS + 2 * c2] = pkrtz(t0, t1);
            }
        }
    }
    wave_fence();

    const int quad = lane >> 4, l16 = lane & 15;
    f4 acc[4][2];

    // ---- phase 2 (GEMM1): Y1[k][o] = sum_c t[k][c] * cw1[o][c]
    {
        g8 bf[2];
#pragma unroll
        for (int nt = 0; nt < 2; ++nt) {
            const float* wr = cw1 + (nt * 16 + l16) * C_R + quad * 8;
            bf[nt] = pack8(*(const float4*)wr, *(const float4*)(wr + 4));
        }
#pragma unroll
        for (int mt = 0; mt < 4; ++mt) {
            acc[mt][0] = (f4){0.f, 0.f, 0.f, 0.f};
            acc[mt][1] = (f4){0.f, 0.f, 0.f, 0.f};
            const g8 af = *(const g8*)((const __fp16*)tb + (mt * 16 + l16) * RS + quad * 8);
            acc[mt][0] = __builtin_amdgcn_mfma_f32_16x16x32_f16(af, bf[0], acc[mt][0], 0, 0, 0);
            acc[mt][1] = __builtin_amdgcn_mfma_f32_16x16x32_f16(af, bf[1], acc[mt][1], 0, 0, 0);
        }
    }
    wave_fence();

    // ---- BN2 + ReLU on C-frags (col = output channel o, lane-scalar BN), write y2[k][o]
#pragma unroll
    for (int nt = 0; nt < 2; ++nt) {
        const int o = nt * 16 + l16;
        const float iv = bn2_g[o] * rsqrtf(bn2_v[o] + BN_EPS);
        const float bt = bn2_b[o] - bn2_m[o] * iv;
#pragma unroll
        for (int mt = 0; mt < 4; ++mt)
#pragma unroll
            for (int r = 0; r < 4; ++r) {
                const int row = mt * 16 + quad * 4 + r;
                tb[row * RS + o] = (_Float16)fmaxf(acc[mt][nt][r] * iv + bt, 0.f);
            }
    }
    wave_fence();

    // ---- phase 3 (GEMM2): logits[k][h] = cw2_b[h] + sum_o y2[k][o] * cw2[h][o]
    {
        g8 bf[2];
#pragma unroll
        for (int nt = 0; nt < 2; ++nt) {
            const float* wr = cw2 + (nt * 16 + l16) * C_R + quad * 8;
            bf[nt] = pack8(*(const float4*)wr, *(const float4*)(wr + 4));
        }
#pragma unroll
        for (int mt = 0; mt < 4; ++mt) {
            acc[mt][0] = (f4){0.f, 0.f, 0.f, 0.f};
            acc[mt][1] = (f4){0.f, 0.f, 0.f, 0.f};
            const g8 af = *(const g8*)((const __fp16*)tb + (mt * 16 + l16) * RS + quad * 8);
            acc[mt][0] = __builtin_amdgcn_mfma_f32_16x16x32_f16(af, bf[0], acc[mt][0], 0, 0, 0);
            acc[mt][1] = __builtin_amdgcn_mfma_f32_16x16x32_f16(af, bf[1], acc[mt][1], 0, 0, 0);
        }
    }
    wave_fence();

    // ---- phase 4: softmax over k per head h = nt*16+l16; k = mt*16+quad*4+r
#pragma unroll
    for (int nt = 0; nt < 2; ++nt) {
        const float bsv = cw2_b[nt * 16 + l16];
        float m = -1e30f;
#pragma unroll
        for (int mt = 0; mt < 4; ++mt)
#pragma unroll
            for (int r = 0; r < 4; ++r) {
                const int k = mt * 16 + quad * 4 + r;
                const float v = acc[mt][nt][r] + bsv;
                acc[mt][nt][r] = v;
                if (k < K2D) m = fmaxf(m, v);
            }
        m = fmaxf(m, __shfl_xor(m, 16, 64));
        m = fmaxf(m, __shfl_xor(m, 32, 64));
        float s = 0.f;
#pragma unroll
        for (int mt = 0; mt < 4; ++mt)
#pragma unroll
            for (int r = 0; r < 4; ++r) {
                const int k = mt * 16 + quad * 4 + r;
                const float e = (k < K2D) ? __expf(acc[mt][nt][r] - m) : 0.f;
                acc[mt][nt][r] = e;
                s += e;
            }
        s += __shfl_xor(s, 16, 64);
        s += __shfl_xor(s, 32, 64);
        const float rs = 1.f / s;
        const int o = nt * 16 + l16;
#pragma unroll
        for (int mt = 0; mt < 4; ++mt)
#pragma unroll
            for (int r = 0; r < 4; ++r) {
                const int row = mt * 16 + quad * 4 + r;
                tb[row * RS + o] = (_Float16)(acc[mt][nt][r] * rs);
            }
    }
    wave_fence();

    // ---- phase 5: out[c] = sum_k x3[pk[k]][c] * wgt[k][c>>3]; c = 4*lane..+3
    {
        const int hn = lane >> 1;     // (4*lane)/8
        float4 a = make_float4(0.f, 0.f, 0.f, 0.f);
#pragma unroll 7
        for (int k = 0; k < K2D; ++k) {
            const int rp = pk[w][k];
            const float wv = (float)tb[k * RS + hn];
            const float4 v = *(const float4*)(base + (size_t)rp * C_ALL + 64 + lane * 4);
            a.x += v.x * wv; a.y += v.y * wv; a.z += v.z * wv; a.w += v.w * wv;
        }
        *(float4*)(outt + ((size_t)b * HW_N + pos) * C_OUT + lane * 4) = a;
    }
}

// ---------------------------------------------------------------------------
// Kernel 3: transpose [b][i][c] -> [b][c][i]
// ---------------------------------------------------------------------------
__global__ __launch_bounds__(256) void k_transpose(
    const float* __restrict__ in, float* __restrict__ out)
{
    __shared__ float ts[32][33];
    const int tid = threadIdx.x;
    const int b  = blockIdx.z;
    const int i0 = blockIdx.x * 32;
    const int c0 = blockIdx.y * 32;
    const int rr = tid >> 5, cc = tid & 31;
#pragma unroll
    for (int r = 0; r < 4; ++r) {
        const int ii = rr * 4 + r;
        ts[ii][cc] = in[((size_t)b * HW_N + i0 + ii) * C_OUT + c0 + cc];
    }
    __syncthreads();
#pragma unroll
    for (int r = 0; r < 4; ++r) {
        const int ccl = rr * 4 + r;
        out[((size_t)b * C_OUT + c0 + ccl) * HW_N + i0 + cc] = ts[cc][ccl];
    }
}

// ---------------------------------------------------------------------------
extern "C" void kernel_launch(void* const* d_in, const int* in_sizes, int n_in,
                              void* d_out, int out_size, void* d_ws, size_t ws_size,
                              hipStream_t stream)
{
    const float* x     = (const float*)d_in[0];
    const float* w1c   = (const float*)d_in[1];
    const float* b1c   = (const float*)d_in[2];
    const float* w2c   = (const float*)d_in[3];
    const float* b2c   = (const float*)d_in[4];
    const float* w3c   = (const float*)d_in[5];
    const float* b3c   = (const float*)d_in[6];
    const float* bn1_g = (const float*)d_in[7];
    const float* bn1_b = (const float*)d_in[8];
    const float* bn1_m = (const float*)d_in[9];
    const float* bn1_v = (const float*)d_in[10];
    const float* cw1   = (const float*)d_in[11];
    const float* bn2_g = (const float*)d_in[12];
    const float* bn2_b = (const float*)d_in[13];
    const float* bn2_m = (const float*)d_in[14];
    const float* bn2_v = (const float*)d_in[15];
    const float* cw2   = (const float*)d_in[16];
    const float* cw2_b = (const float*)d_in[17];

    float* xall = (float*)d_ws;                              // [4][3136][320] f32
    float* outt = xall + (size_t)4 * HW_N * C_ALL;           // [4][3136][256] f32
    // xT16/wh alias the outt region: dead before k_attn writes outt.
    __fp16* xT16 = (__fp16*)outt;                            // [4][3136][256] f16
    __fp16* wh   = xT16 + (size_t)4 * HW_N * C_IN;           // [320][256] f16

    k_prep_w<<<80, 256, 0, stream>>>(w1c, w2c, w3c, wh);
    k_prep_x<<<dim3(49, 2, 4), 256, 0, stream>>>(x, xT16);
    k_conv_mfma<<<dim3(49, 5, 4), 256, 0, stream>>>(xT16, wh, b1c, b2c, b3c, xall);
    k_attn<<<dim3(784, 4, 1), 256, 0, stream>>>(xall,
        bn1_g, bn1_b, bn1_m, bn1_v, cw1,
        bn2_g, bn2_b, bn2_m, bn2_v, cw2, cw2_b, outt);
    k_transpose<<<dim3(98, 8, 4), 256, 0, stream>>>(outt, (float*)d_out);
}

// Round 7
// 167.712 us; speedup vs baseline: 1.8786x; 1.0095x over previous
//
#include <hip/hip_runtime.h>
#include <math.h>

#define HW_N   3136
#define W_DIM  56
#define C_IN   256
#define C_R    32
#define C_OUT  256
#define C_ALL  320
#define K2D    49
#define RS     40        // attn t-row stride in halfs (80 B, 16B-aligned)
#define BN_EPS 1e-5f

typedef _Float16 h2 __attribute__((ext_vector_type(2)));
typedef __fp16  g2 __attribute__((ext_vector_type(2)));   // cvt_pkrtz return type
typedef __fp16  g4 __attribute__((ext_vector_type(4)));
typedef __fp16  g8 __attribute__((ext_vector_type(8)));
typedef float   f4 __attribute__((ext_vector_type(4)));

__device__ __forceinline__ h2 pkrtz(float a, float b) {
    g2 r = __builtin_amdgcn_cvt_pkrtz(a, b);
    return __builtin_bit_cast(h2, r);
}

__device__ __forceinline__ g8 pack8(float4 a, float4 b) {
    g2 p0 = __builtin_amdgcn_cvt_pkrtz(a.x, a.y);
    g2 p1 = __builtin_amdgcn_cvt_pkrtz(a.z, a.w);
    g2 p2 = __builtin_amdgcn_cvt_pkrtz(b.x, b.y);
    g2 p3 = __builtin_amdgcn_cvt_pkrtz(b.z, b.w);
    g8 o;
    o[0] = p0[0]; o[1] = p0[1]; o[2] = p1[0]; o[3] = p1[1];
    o[4] = p2[0]; o[5] = p2[1]; o[6] = p3[0]; o[7] = p3[1];
    return o;
}

__device__ __forceinline__ int refl(int v) {
    v = (v < 0) ? -v : v;
    return (v > 55) ? (110 - v) : v;
}

// Wave-local "barrier": tbuf[w]/pk[w] are wave-private; DS pipe is in-order
// per wave, so we only need the compiler fence + lgkmcnt drain.
__device__ __forceinline__ void wave_fence() {
    asm volatile("s_waitcnt lgkmcnt(0)" ::: "memory");
}

// ---------------------------------------------------------------------------
// Kernel 0: transpose+convert x[b][ci][pos] f32 -> xT16[b][pos][ci] f16.
// ---------------------------------------------------------------------------
__global__ __launch_bounds__(256) void k_prep_x(
    const float* __restrict__ x, __fp16* __restrict__ xT16)
{
    const int t   = threadIdx.x;
    const int b   = blockIdx.z;
    const int pos = blockIdx.x * 64 + (t & 63);
    const int ci0 = (blockIdx.y * 4 + (t >> 6)) * 32;
    const float* __restrict__ xp = x + ((size_t)b * C_IN + ci0) * HW_N + pos;
    float v[32];
#pragma unroll
    for (int j = 0; j < 32; ++j) v[j] = xp[(size_t)j * HW_N];
    __fp16* op = xT16 + ((size_t)b * HW_N + pos) * C_IN + ci0;
#pragma unroll
    for (int q = 0; q < 4; ++q) {
        g8 o;
#pragma unroll
        for (int i = 0; i < 4; ++i) {
            const g2 p = __builtin_amdgcn_cvt_pkrtz(v[q * 8 + 2 * i], v[q * 8 + 2 * i + 1]);
            o[2 * i] = p[0]; o[2 * i + 1] = p[1];
        }
        *(g8*)(op + q * 8) = o;
    }
}

// ---------------------------------------------------------------------------
// Kernel 1: MFMA conv1x1 -> xall16[b][pos][320] f16.
// B-frags packed from f32 weights in-register (k_prep_w folded in).
// Epilogue repacks C-frags through LDS for co-contiguous f16 stores.
// ---------------------------------------------------------------------------
__global__ __launch_bounds__(256) void k_conv_mfma(
    const __fp16* __restrict__ xT16,
    const float* __restrict__ w1c, const float* __restrict__ w2c,
    const float* __restrict__ w3c,
    const float* __restrict__ b1c, const float* __restrict__ b2c,
    const float* __restrict__ b3c, __fp16* __restrict__ xall16)
{
    __shared__ __align__(16) float cs[64][68];
    const int t = threadIdx.x, w = t >> 6, lane = t & 63;
    const int quad = lane >> 4, l16 = lane & 15;
    const int b = blockIdx.z, pos0 = blockIdx.x * 64, co0 = blockIdx.y * 64;
    const int co_row = co0 + w * 16 + l16;

    const float* wp = (co_row < 32) ? (w1c + co_row * C_IN)
                    : (co_row < 64) ? (w2c + (co_row - 32) * C_IN)
                                    : (w3c + (co_row - 64) * C_IN);
    const float bias = (co_row < 32) ? b1c[co_row]
                     : (co_row < 64) ? b2c[co_row - 32] : b3c[co_row - 64];

    const __fp16* arow = xT16 + ((size_t)b * HW_N + pos0 + l16) * C_IN + quad * 8;
    const float* brow = wp + quad * 8;

    f4 acc[4];
#pragma unroll
    for (int mt = 0; mt < 4; ++mt) acc[mt] = (f4){0.f, 0.f, 0.f, 0.f};

#pragma unroll
    for (int ks = 0; ks < 8; ++ks) {
        const g8 bf = pack8(*(const float4*)(brow + ks * 32),
                            *(const float4*)(brow + ks * 32 + 4));
#pragma unroll
        for (int mt = 0; mt < 4; ++mt) {
            const g8 af = *(const g8*)(arow + (size_t)mt * 16 * C_IN + ks * 32);
            acc[mt] = __builtin_amdgcn_mfma_f32_16x16x32_f16(af, bf, acc[mt], 0, 0, 0);
        }
    }

    // C-frags -> LDS f32 (col = local co, row = pos), then repack to f16
#pragma unroll
    for (int mt = 0; mt < 4; ++mt)
#pragma unroll
        for (int r = 0; r < 4; ++r)
            cs[mt * 16 + quad * 4 + r][w * 16 + l16] = acc[mt][r] + bias;
    __syncthreads();

    const int pr = t >> 2, cq = (t & 3) * 16;
    const float4 v0 = *(const float4*)&cs[pr][cq];
    const float4 v1 = *(const float4*)&cs[pr][cq + 4];
    const float4 v2 = *(const float4*)&cs[pr][cq + 8];
    const float4 v3 = *(const float4*)&cs[pr][cq + 12];
    __fp16* op = xall16 + ((size_t)b * HW_N + pos0 + pr) * C_ALL + co0 + cq;
    *(g8*)op = pack8(v0, v1);
    *(g8*)(op + 8) = pack8(v2, v3);
}

// ---------------------------------------------------------------------------
// Kernel 2: fused attention + output transpose. One wave per pixel,
// 4 waves/block; single block barrier at the very end for the transpose.
// ---------------------------------------------------------------------------
__global__ __launch_bounds__(256) void k_attn(
    const __fp16* __restrict__ xq,
    const float* __restrict__ bn1_g, const float* __restrict__ bn1_b,
    const float* __restrict__ bn1_m, const float* __restrict__ bn1_v,
    const float* __restrict__ cw1,
    const float* __restrict__ bn2_g, const float* __restrict__ bn2_b,
    const float* __restrict__ bn2_m, const float* __restrict__ bn2_v,
    const float* __restrict__ cw2, const float* __restrict__ cw2_b,
    float* __restrict__ out)
{
    __shared__ __align__(16) _Float16 tbuf[4][64 * RS];   // 64 rows (49 valid)
    __shared__ __align__(16) float stage[4][256];
    __shared__ int pk[4][52];
    const int tid = threadIdx.x;
    const int w = tid >> 6, lane = tid & 63;
    const int b = blockIdx.y;
    const int bid  = blockIdx.x;                 // 0..783
    const int posb = (bid & 7) * 98 + (bid >> 3);   // XCD-contiguous spans
    const int pos0 = posb * 4;
    const int pos  = pos0 + w;
    const int y0 = pos / W_DIM, x0 = pos - y0 * W_DIM;
    const __fp16* __restrict__ base16 = xq + (size_t)b * HW_N * C_ALL;
    _Float16* tb = tbuf[w];

    // ---- phase 1: t[k][c] = relu(bn1(x1[c] - x2[pk(k)][c])), f16-packed
    {
        const int c2 = lane & 15;        // channel pair
        const int kh = lane >> 4;        // k mod 4 group
        const float2 g = *(const float2*)(bn1_g + 2 * c2);
        const float2 bb = *(const float2*)(bn1_b + 2 * c2);
        const float2 m = *(const float2*)(bn1_m + 2 * c2);
        const float2 v = *(const float2*)(bn1_v + 2 * c2);
        const float iv0 = g.x * rsqrtf(v.x + BN_EPS), bt0 = bb.x - m.x * iv0;
        const float iv1 = g.y * rsqrtf(v.y + BN_EPS), bt1 = bb.y - m.y * iv1;
        const g2 x1p = *(const g2*)(base16 + (size_t)pos * C_ALL + 2 * c2);
        const float x1a = (float)x1p[0], x1b = (float)x1p[1];
#pragma unroll
        for (int j = 0; j < 13; ++j) {
            const int k = 4 * j + kh;
            if (k < K2D) {
                const int dy = k / 7, dx = k - dy * 7;
                const int rp = refl(y0 + dy - 3) * W_DIM + refl(x0 + dx - 3);
                if (c2 == 0) pk[w][k] = rp;
                const g2 x2p = *(const g2*)(base16 + (size_t)rp * C_ALL + 32 + 2 * c2);
                const float t0 = fmaxf((x1a - (float)x2p[0]) * iv0 + bt0, 0.f);
                const float t1 = fmaxf((x1b - (float)x2p[1]) * iv1 + bt1, 0.f);
                *(h2*)&tb[k * RS + 2 * c2] = pkrtz(t0, t1);
            }
        }
    }
    wave_fence();

    const int quad = lane >> 4, l16 = lane & 15;
    f4 acc[4][2];

    // ---- phase 2 (GEMM1): Y1[k][o] = sum_c t[k][c] * cw1[o][c]
    {
        g8 bf[2];
#pragma unroll
        for (int nt = 0; nt < 2; ++nt) {
            const float* wr = cw1 + (nt * 16 + l16) * C_R + quad * 8;
            bf[nt] = pack8(*(const float4*)wr, *(const float4*)(wr + 4));
        }
#pragma unroll
        for (int mt = 0; mt < 4; ++mt) {
            acc[mt][0] = (f4){0.f, 0.f, 0.f, 0.f};
            acc[mt][1] = (f4){0.f, 0.f, 0.f, 0.f};
            const g8 af = *(const g8*)((const __fp16*)tb + (mt * 16 + l16) * RS + quad * 8);
            acc[mt][0] = __builtin_amdgcn_mfma_f32_16x16x32_f16(af, bf[0], acc[mt][0], 0, 0, 0);
            acc[mt][1] = __builtin_amdgcn_mfma_f32_16x16x32_f16(af, bf[1], acc[mt][1], 0, 0, 0);
        }
    }
    wave_fence();

    // ---- BN2 + ReLU on C-frags (col = output channel o), write y2[k][o]
#pragma unroll
    for (int nt = 0; nt < 2; ++nt) {
        const int o = nt * 16 + l16;
        const float iv = bn2_g[o] * rsqrtf(bn2_v[o] + BN_EPS);
        const float bt = bn2_b[o] - bn2_m[o] * iv;
#pragma unroll
        for (int mt = 0; mt < 4; ++mt)
#pragma unroll
            for (int r = 0; r < 4; ++r) {
                const int row = mt * 16 + quad * 4 + r;
                tb[row * RS + o] = (_Float16)fmaxf(acc[mt][nt][r] * iv + bt, 0.f);
            }
    }
    wave_fence();

    // ---- phase 3 (GEMM2): logits[k][h] = cw2_b[h] + sum_o y2[k][o] * cw2[h][o]
    {
        g8 bf[2];
#pragma unroll
        for (int nt = 0; nt < 2; ++nt) {
            const float* wr = cw2 + (nt * 16 + l16) * C_R + quad * 8;
            bf[nt] = pack8(*(const float4*)wr, *(const float4*)(wr + 4));
        }
#pragma unroll
        for (int mt = 0; mt < 4; ++mt) {
            acc[mt][0] = (f4){0.f, 0.f, 0.f, 0.f};
            acc[mt][1] = (f4){0.f, 0.f, 0.f, 0.f};
            const g8 af = *(const g8*)((const __fp16*)tb + (mt * 16 + l16) * RS + quad * 8);
            acc[mt][0] = __builtin_amdgcn_mfma_f32_16x16x32_f16(af, bf[0], acc[mt][0], 0, 0, 0);
            acc[mt][1] = __builtin_amdgcn_mfma_f32_16x16x32_f16(af, bf[1], acc[mt][1], 0, 0, 0);
        }
    }
    wave_fence();

    // ---- phase 4: softmax over k per head h = nt*16+l16; k = mt*16+quad*4+r
#pragma unroll
    for (int nt = 0; nt < 2; ++nt) {
        const float bsv = cw2_b[nt * 16 + l16];
        float m = -1e30f;
#pragma unroll
        for (int mt = 0; mt < 4; ++mt)
#pragma unroll
            for (int r = 0; r < 4; ++r) {
                const int k = mt * 16 + quad * 4 + r;
                const float v = acc[mt][nt][r] + bsv;
                acc[mt][nt][r] = v;
                if (k < K2D) m = fmaxf(m, v);
            }
        m = fmaxf(m, __shfl_xor(m, 16, 64));
        m = fmaxf(m, __shfl_xor(m, 32, 64));
        float s = 0.f;
#pragma unroll
        for (int mt = 0; mt < 4; ++mt)
#pragma unroll
            for (int r = 0; r < 4; ++r) {
                const int k = mt * 16 + quad * 4 + r;
                const float e = (k < K2D) ? __expf(acc[mt][nt][r] - m) : 0.f;
                acc[mt][nt][r] = e;
                s += e;
            }
        s += __shfl_xor(s, 16, 64);
        s += __shfl_xor(s, 32, 64);
        const float rs = 1.f / s;
        const int o = nt * 16 + l16;
#pragma unroll
        for (int mt = 0; mt < 4; ++mt)
#pragma unroll
            for (int r = 0; r < 4; ++r) {
                const int row = mt * 16 + quad * 4 + r;
                tb[row * RS + o] = (_Float16)(acc[mt][nt][r] * rs);
            }
    }
    wave_fence();

    // ---- phase 5: out[c] = sum_k x3[pk[k]][c] * wgt[k][c>>3]; c = 4*lane..+3
    {
        const int hn = lane >> 1;     // (4*lane)/8
        float4 a = make_float4(0.f, 0.f, 0.f, 0.f);
#pragma unroll 7
        for (int k = 0; k < K2D; ++k) {
            const int rp = pk[w][k];
            const float wv = (float)tb[k * RS + hn];
            const g4 v = *(const g4*)(base16 + (size_t)rp * C_ALL + 64 + lane * 4);
            a.x += (float)v[0] * wv; a.y += (float)v[1] * wv;
            a.z += (float)v[2] * wv; a.w += (float)v[3] * wv;
        }
        *(float4*)&stage[w][lane * 4] = a;
    }
    __syncthreads();

    // ---- transpose through LDS: store out[b][c][pos0..pos0+3]
    {
        const int c = tid;
        float4 o;
        o.x = stage[0][c]; o.y = stage[1][c];
        o.z = stage[2][c]; o.w = stage[3][c];
        *(float4*)(out + ((size_t)b * C_OUT + c) * HW_N + pos0) = o;
    }
}

// ---------------------------------------------------------------------------
extern "C" void kernel_launch(void* const* d_in, const int* in_sizes, int n_in,
                              void* d_out, int out_size, void* d_ws, size_t ws_size,
                              hipStream_t stream)
{
    const float* x     = (const float*)d_in[0];
    const float* w1c   = (const float*)d_in[1];
    const float* b1c   = (const float*)d_in[2];
    const float* w2c   = (const float*)d_in[3];
    const float* b2c   = (const float*)d_in[4];
    const float* w3c   = (const float*)d_in[5];
    const float* b3c   = (const float*)d_in[6];
    const float* bn1_g = (const float*)d_in[7];
    const float* bn1_b = (const float*)d_in[8];
    const float* bn1_m = (const float*)d_in[9];
    const float* bn1_v = (const float*)d_in[10];
    const float* cw1   = (const float*)d_in[11];
    const float* bn2_g = (const float*)d_in[12];
    const float* bn2_b = (const float*)d_in[13];
    const float* bn2_m = (const float*)d_in[14];
    const float* bn2_v = (const float*)d_in[15];
    const float* cw2   = (const float*)d_in[16];
    const float* cw2_b = (const float*)d_in[17];

    __fp16* xT16   = (__fp16*)d_ws;                         // [4][3136][256] f16
    __fp16* xall16 = xT16 + (size_t)4 * HW_N * C_IN;        // [4][3136][320] f16

    k_prep_x<<<dim3(49, 2, 4), 256, 0, stream>>>(x, xT16);
    k_conv_mfma<<<dim3(49, 5, 4), 256, 0, stream>>>(xT16, w1c, w2c, w3c,
                                                    b1c, b2c, b3c, xall16);
    k_attn<<<dim3(784, 4, 1), 256, 0, stream>>>(xall16,
        bn1_g, bn1_b, bn1_m, bn1_v, cw1,
        bn2_g, bn2_b, bn2_m, bn2_v, cw2, cw2_b, (float*)d_out);
}